// Round 6
// baseline (330.368 us; speedup 1.0000x reference)
//
#include <hip/hip_runtime.h>

#define N_NODES 100000
#define N_EDGES 1200000
#define NF 64

typedef __attribute__((ext_vector_type(8))) short short8;
typedef __attribute__((ext_vector_type(4))) float float4v;

__device__ __forceinline__ ushort f2bf(float f) {
    unsigned u = __float_as_uint(f);
    return (ushort)((u + 0x7FFF + ((u >> 16) & 1)) >> 16);  // RNE
}
__device__ __forceinline__ float bf2f(ushort b) {
    return __uint_as_float(((unsigned)b) << 16);
}

// binning: bin = node >> 9, 196 bins of 512 nodes
#define NBINS 196
#define EPB 5120
#define NBLK 235            // ceil(1200000/5120)

// ---------------- workspace layout (bytes), peak ~36.4 MB ----------------
#define OFF_DINV    0            // float[100000]
#define OFF_CNT     400128       // int[100000]
#define OFF_ENDP    800256       // int[100000]
#define OFF_COUNTS  1200384      // int[392]  (global-atomic histogram)
#define OFF_OFFS    1202048      // int[392]  (exclusive scan, stable)
#define OFF_GCUR    1203712      // int[392]  (mutable cursors; dst half rebased by -E1)
#define OFF_PKW     1205376      // ushort[2*16*64*8] = 32 KB packed B-fragments
#define OFF_CSR     1238400      // int2[1200000] = 9.6 MB
#define OFF_SCRATCH 10838400
//   sbinned : SCRATCH + 0        int[1200000]  (4.8 MB)   } dead after binD1/D2
//   dbinned : SCRATCH + 4800000  int2[1200000] (9.6 MB)   }
//   emb_bf  : SCRATCH + 0        ushort[6.4M] (12.8 MB)   } after binD2
//   h_bf    : SCRATCH + 12800000 ushort[6.4M] (12.8 MB)   }

// Phase A: per-block LDS histograms -> 392 global atomic adds per block
__global__ __launch_bounds__(256) void binA(const int* __restrict__ row,
                                            const int* __restrict__ col,
                                            int* __restrict__ counts) {
    __shared__ int sh[NBINS], dh[NBINS];
    int t = threadIdx.x;
    if (t < NBINS) { sh[t] = 0; dh[t] = 0; }
    __syncthreads();
    int base = blockIdx.x * EPB;
    for (int k = 0; k < 20; ++k) {
        int e = base + k * 256 + t;
        if (e < N_EDGES) {
            int s = row[e], d = col[e];
            if (s != d) {
                atomicAdd(&sh[s >> 9], 1);
                atomicAdd(&dh[d >> 9], 1);
            }
        }
    }
    __syncthreads();
    if (t < NBINS) {
        if (sh[t]) atomicAdd(&counts[t], sh[t]);
        if (dh[t]) atomicAdd(&counts[NBINS + t], dh[t]);
    }
}

// single-block exclusive scan of counts[392] -> offs, gcur (dst half rebased -E1)
__global__ __launch_bounds__(512) void scan392(const int* __restrict__ counts,
                                               int* __restrict__ offs,
                                               int* __restrict__ gcur) {
    __shared__ int s[512];
    __shared__ int e1s;
    int t = threadIdx.x;
    int v = (t < 2 * NBINS) ? counts[t] : 0;
    s[t] = v;
    __syncthreads();
    for (int off = 1; off < 512; off <<= 1) {
        int a = (t >= off) ? s[t - off] : 0;
        __syncthreads();
        s[t] += a;
        __syncthreads();
    }
    int ex = s[t] - v;
    if (t == NBINS) e1s = ex;
    __syncthreads();
    if (t < 2 * NBINS) {
        offs[t] = ex;
        gcur[t] = (t < NBINS) ? ex : (ex - e1s);
    }
}

// Phase C: scatter with LDS write-combining rings (16 entries/bin, flush by 8)
__global__ __launch_bounds__(256) void binC(const int* __restrict__ row,
                                            const int* __restrict__ col,
                                            int* __restrict__ gcur,
                                            int* __restrict__ sbinned,
                                            int2* __restrict__ dbinned) {
    __shared__ int2 dring[NBINS][16];
    __shared__ int  sring[NBINS][16];
    __shared__ int  scnt[NBINS], sflush[NBINS], dcnt[NBINS], dflush[NBINS];
    __shared__ int  again;
    int t = threadIdx.x;
    if (t < NBINS) { scnt[t] = 0; sflush[t] = 0; dcnt[t] = 0; dflush[t] = 0; }
    __syncthreads();

    int base = blockIdx.x * EPB;
    for (int k = 0; k < 20; ++k) {
        int e = base + k * 256 + t;
        bool have_s = false, have_d = false;
        int s = 0, d = 0;
        if (e < N_EDGES) {
            s = row[e]; d = col[e];
            if (s != d) { have_s = true; have_d = true; }
        }
        while (true) {
            if (t == 0) again = 0;
            __syncthreads();
            if (have_s) {
                int b = s >> 9;
                int p = atomicAdd(&scnt[b], 1);
                if (p - sflush[b] < 16) { sring[b][p & 15] = s; have_s = false; }
                else { atomicSub(&scnt[b], 1); again = 1; }
            }
            if (have_d) {
                int b = d >> 9;
                int p = atomicAdd(&dcnt[b], 1);
                if (p - dflush[b] < 16) { dring[b][p & 15] = make_int2(s, d); have_d = false; }
                else { atomicSub(&dcnt[b], 1); again = 1; }
            }
            __syncthreads();
            if (t < NBINS) {
                int c = scnt[t], f = sflush[t];
                while (c - f >= 8) {
                    int g = atomicAdd(&gcur[t], 8);
#pragma unroll
                    for (int i = 0; i < 8; ++i) sbinned[g + i] = sring[t][(f + i) & 15];
                    f += 8;
                }
                sflush[t] = f;
                c = dcnt[t]; f = dflush[t];
                while (c - f >= 8) {
                    int g = atomicAdd(&gcur[NBINS + t], 8);
#pragma unroll
                    for (int i = 0; i < 8; ++i) dbinned[g + i] = dring[t][(f + i) & 15];
                    f += 8;
                }
                dflush[t] = f;
            }
            __syncthreads();
            if (!again) break;
        }
    }
    // residual flush (<8 entries per bin)
    if (t < NBINS) {
        int c = scnt[t], f = sflush[t];
        if (c > f) {
            int g = atomicAdd(&gcur[t], c - f);
            for (; f < c; ++f) sbinned[g++] = sring[t][f & 15];
        }
        c = dcnt[t]; f = dflush[t];
        if (c > f) {
            int g = atomicAdd(&gcur[NBINS + t], c - f);
            for (; f < c; ++f) dbinned[g++] = dring[t][f & 15];
        }
    }
}

// Phase D1: per src-bin per-node histogram -> dinv (coalesced)
__global__ __launch_bounds__(256) void binD1(const int* __restrict__ sbinned,
                                             const int* __restrict__ offs,
                                             float* __restrict__ dinv) {
    __shared__ int hist[512];
    int t = threadIdx.x;
    hist[t] = 0; hist[t + 256] = 0;
    __syncthreads();
    int b = blockIdx.x;
    int start = offs[b];
    int end = offs[b + 1];   // b=195 -> offs[196] == E1
    for (int i = start + t; i < end; i += 256)
        atomicAdd(&hist[sbinned[i] - (b << 9)], 1);
    __syncthreads();
    int n0 = (b << 9) + t, n1 = n0 + 256;
    if (n0 < N_NODES) dinv[n0] = hist[t] ? rsqrtf((float)hist[t]) : 0.0f;
    if (n1 < N_NODES) dinv[n1] = hist[t + 256] ? rsqrtf((float)hist[t + 256]) : 0.0f;
}

// Phase D2: per dst-bin histogram + LDS scan -> cnt/endp + CSR placement
__global__ __launch_bounds__(256) void binD2(const int2* __restrict__ dbinned,
                                             const int* __restrict__ offs,
                                             const float* __restrict__ dinv,
                                             int* __restrict__ cnt,
                                             int* __restrict__ endp,
                                             int2* __restrict__ csr) {
    __shared__ int hist[512];
    __shared__ int lcur[512];
    int t = threadIdx.x;
    hist[t] = 0; hist[t + 256] = 0;
    __syncthreads();
    int b = blockIdx.x;
    int E1 = offs[NBINS];
    int start = offs[NBINS + b] - E1;
    int end = (b == NBINS - 1) ? E1 : (offs[NBINS + b + 1] - E1);
    for (int i = start + t; i < end; i += 256)
        atomicAdd(&hist[dbinned[i].y - (b << 9)], 1);
    __syncthreads();
    int o0 = hist[t], o1 = hist[t + 256];
    for (int off = 1; off < 512; off <<= 1) {
        int v0 = (t >= off) ? hist[t - off] : 0;
        int v1 = (t + 256 >= off) ? hist[t + 256 - off] : 0;
        __syncthreads();
        hist[t] += v0; hist[t + 256] += v1;
        __syncthreads();
    }
    int e0 = hist[t] - o0, e1 = hist[t + 256] - o1;
    lcur[t] = start + e0;
    lcur[t + 256] = start + e1;
    int n0 = (b << 9) + t, n1 = n0 + 256;
    if (n0 < N_NODES) { cnt[n0] = o0; endp[n0] = start + e0 + o0; }
    if (n1 < N_NODES) { cnt[n1] = o1; endp[n1] = start + e1 + o1; }
    __syncthreads();
    for (int i = start + t; i < end; i += 256) {
        int2 r = dbinned[i];
        int slot = atomicAdd(&lcur[r.y - (b << 9)], 1);
        float nrm = -dinv[r.x] * dinv[r.y];
        csr[slot] = make_int2(r.x, __float_as_int(nrm));
    }
}

// emb f32 -> bf16 (RNE)
__global__ __launch_bounds__(256) void embcvt(const float* __restrict__ in,
                                              ushort* __restrict__ out) {
    int i = (blockIdx.x * 256 + threadIdx.x) * 4;
    float4 v = *(const float4*)(in + i);
    ushort4 o;
    o.x = f2bf(v.x); o.y = f2bf(v.y); o.z = f2bf(v.z); o.w = f2bf(v.w);
    *(ushort4*)(out + i) = o;
}

// pack both layers' B=[W0;W1] (128x64 f32) into MFMA B-fragment order (bf16)
// pk[(layer*1024 + f*64 + L)*8 + j] = B[k][n], k=(f>>2)*32+((L>>4)<<3)+j, n=(f&3)*16+(L&15)
__global__ __launch_bounds__(256) void packW(const float* __restrict__ W10,
                                             const float* __restrict__ W11,
                                             const float* __restrict__ W20,
                                             const float* __restrict__ W21,
                                             ushort* __restrict__ pk) {
    int idx = blockIdx.x * 256 + threadIdx.x;   // [0, 2048)
    int layer = idx >> 10;
    int rest = idx & 1023;
    int f = rest >> 6, L = rest & 63;
    int n = (f & 3) * 16 + (L & 15);
    int kb = (f >> 2) * 32 + ((L >> 4) << 3);
#pragma unroll
    for (int j = 0; j < 8; ++j) {
        int k = kb + j;
        const float* W = layer ? ((k < 64) ? W20 : W21) : ((k < 64) ? W10 : W11);
        float v = W[(k & 63) * 64 + n];
        pk[idx * 8 + j] = f2bf(v);
    }
}

// Fused layer: 16 nodes/wave aggregation (bf16 gather, pipelined csr) + MFMA.
// LDS = sA only (34.8 KB) -> 4 blocks/CU; no __syncthreads (waves independent).
#define NPW 16
#define WPB 8
#define NPB (NPW * WPB)                       // 128
#define LB2 ((N_NODES + NPB - 1) / NPB)       // 782

__global__ __launch_bounds__(512, 7) void cheb_layer(const ushort* __restrict__ x,
                                                     const int2* __restrict__ csr,
                                                     const int* __restrict__ endp,
                                                     const int* __restrict__ cnt,
                                                     const ushort* __restrict__ pk,
                                                     const float* __restrict__ bias,
                                                     ushort* __restrict__ out_bf,
                                                     float* __restrict__ out_f32,
                                                     int last) {
    __shared__ ushort sA[WPB][16][136];   // 34.8 KB

    int t = threadIdx.x;
    int lane = t & 63, wid = t >> 6;
    int c = lane & 15, q = lane >> 4;
    int nb = blockIdx.x * NPB + wid * NPW;

    int nend = 0, ncnt = 0;
    if (lane < NPW && nb + lane < N_NODES) {
        nend = endp[nb + lane];
        ncnt = cnt[nb + lane];
    }

    // ---- aggregate 16 nodes, stage A = [x | Tx1] per node ----
    for (int g = 0; g < NPW; ++g) {
        int node = nb + g;
        int cn = __builtin_amdgcn_readlane(ncnt, g);
        int eend = __builtin_amdgcn_readlane(nend, g);
        int e = eend - cn;
        ushort xb = (node < N_NODES) ? x[(size_t)node * NF + lane] : (ushort)0;
        float a0 = 0, a1 = 0, a2 = 0, a3 = 0, a4 = 0, a5 = 0, a6 = 0, a7 = 0;
        int full = cn >> 3;
        if (full) {
            int2 q0 = csr[e + 0], q1 = csr[e + 1], q2 = csr[e + 2], q3 = csr[e + 3];
            int2 q4 = csr[e + 4], q5 = csr[e + 5], q6 = csr[e + 6], q7 = csr[e + 7];
            for (int it = 1; it < full; ++it) {
                // issue gathers for current batch
                float g0 = bf2f(x[(size_t)q0.x * NF + lane]);
                float g1 = bf2f(x[(size_t)q1.x * NF + lane]);
                float g2 = bf2f(x[(size_t)q2.x * NF + lane]);
                float g3 = bf2f(x[(size_t)q3.x * NF + lane]);
                float g4 = bf2f(x[(size_t)q4.x * NF + lane]);
                float g5 = bf2f(x[(size_t)q5.x * NF + lane]);
                float g6 = bf2f(x[(size_t)q6.x * NF + lane]);
                float g7 = bf2f(x[(size_t)q7.x * NF + lane]);
                // prefetch next csr batch (independent -> stays in flight)
                int2 r0 = csr[e + 8],  r1 = csr[e + 9],  r2 = csr[e + 10], r3 = csr[e + 11];
                int2 r4 = csr[e + 12], r5 = csr[e + 13], r6 = csr[e + 14], r7 = csr[e + 15];
                a0 = fmaf(__int_as_float(q0.y), g0, a0);
                a1 = fmaf(__int_as_float(q1.y), g1, a1);
                a2 = fmaf(__int_as_float(q2.y), g2, a2);
                a3 = fmaf(__int_as_float(q3.y), g3, a3);
                a4 = fmaf(__int_as_float(q4.y), g4, a4);
                a5 = fmaf(__int_as_float(q5.y), g5, a5);
                a6 = fmaf(__int_as_float(q6.y), g6, a6);
                a7 = fmaf(__int_as_float(q7.y), g7, a7);
                q0 = r0; q1 = r1; q2 = r2; q3 = r3;
                q4 = r4; q5 = r5; q6 = r6; q7 = r7;
                e += 8;
            }
            a0 = fmaf(__int_as_float(q0.y), bf2f(x[(size_t)q0.x * NF + lane]), a0);
            a1 = fmaf(__int_as_float(q1.y), bf2f(x[(size_t)q1.x * NF + lane]), a1);
            a2 = fmaf(__int_as_float(q2.y), bf2f(x[(size_t)q2.x * NF + lane]), a2);
            a3 = fmaf(__int_as_float(q3.y), bf2f(x[(size_t)q3.x * NF + lane]), a3);
            a4 = fmaf(__int_as_float(q4.y), bf2f(x[(size_t)q4.x * NF + lane]), a4);
            a5 = fmaf(__int_as_float(q5.y), bf2f(x[(size_t)q5.x * NF + lane]), a5);
            a6 = fmaf(__int_as_float(q6.y), bf2f(x[(size_t)q6.x * NF + lane]), a6);
            a7 = fmaf(__int_as_float(q7.y), bf2f(x[(size_t)q7.x * NF + lane]), a7);
            e += 8;
        }
        for (; e < eend; ++e) {
            int2 p = csr[e];
            a0 = fmaf(__int_as_float(p.y), bf2f(x[(size_t)p.x * NF + lane]), a0);
        }
        float acc = ((a0 + a1) + (a2 + a3)) + ((a4 + a5) + (a6 + a7));
        sA[wid][g][lane] = xb;
        sA[wid][g][64 + lane] = f2bf(acc);
    }
    __builtin_amdgcn_wave_barrier();

    // ---- MFMA: C[16x64] = A[16x128] * B[128x64] + bias (B-frags from global) ----
    const short8* pk8 = (const short8*)pk;
    float4v C[4];
#pragma unroll
    for (int nt = 0; nt < 4; ++nt) {
        float b = bias[nt * 16 + c];
        C[nt] = (float4v){b, b, b, b};
    }
#pragma unroll
    for (int kt = 0; kt < 4; ++kt) {
        short8 af = *(const short8*)&sA[wid][c][kt * 32 + q * 8];
#pragma unroll
        for (int nt = 0; nt < 4; ++nt) {
            short8 bfr = pk8[(kt * 4 + nt) * 64 + lane];
            C[nt] = __builtin_amdgcn_mfma_f32_16x16x32_bf16(af, bfr, C[nt], 0, 0, 0);
        }
    }

    // ---- store: row m = q*4+i, col n = nt*16+c ----
#pragma unroll
    for (int nt = 0; nt < 4; ++nt) {
#pragma unroll
        for (int i = 0; i < 4; ++i) {
            int node = nb + q * 4 + i;
            if (node < N_NODES) {
                float v = C[nt][i];
                if (!last) {
                    v = fmaxf(v, 0.0f);
                    out_bf[(size_t)node * NF + nt * 16 + c] = f2bf(v);
                } else {
                    out_f32[(size_t)node * NF + nt * 16 + c] = v;
                }
            }
        }
    }
}

extern "C" void kernel_launch(void* const* d_in, const int* in_sizes, int n_in,
                              void* d_out, int out_size, void* d_ws, size_t ws_size,
                              hipStream_t stream) {
    const int* ei = (const int*)d_in[0];
    const int* row = ei;
    const int* col = ei + N_EDGES;
    const float* emb = (const float*)d_in[1];
    const float* W1_0 = (const float*)d_in[2];
    const float* W1_1 = (const float*)d_in[3];
    const float* b1 = (const float*)d_in[4];
    const float* W2_0 = (const float*)d_in[5];
    const float* W2_1 = (const float*)d_in[6];
    const float* b2 = (const float*)d_in[7];
    float* out = (float*)d_out;

    char* ws = (char*)d_ws;
    float* dinv = (float*)(ws + OFF_DINV);
    int* cnt = (int*)(ws + OFF_CNT);
    int* endp = (int*)(ws + OFF_ENDP);
    int* counts = (int*)(ws + OFF_COUNTS);
    int* offs = (int*)(ws + OFF_OFFS);
    int* gcur = (int*)(ws + OFF_GCUR);
    ushort* pk = (ushort*)(ws + OFF_PKW);
    int2* csr = (int2*)(ws + OFF_CSR);
    char* scratch = ws + OFF_SCRATCH;
    int* sbinned = (int*)(scratch);
    int2* dbinned = (int2*)(scratch + 4800000);
    ushort* emb_bf = (ushort*)(scratch);              // after binD1/binD2
    ushort* h_bf = (ushort*)(scratch + 12800000);     // after binD2

    hipMemsetAsync(counts, 0, 2 * NBINS * sizeof(int), stream);
    binA<<<NBLK, 256, 0, stream>>>(row, col, counts);
    scan392<<<1, 512, 0, stream>>>(counts, offs, gcur);
    binC<<<NBLK, 256, 0, stream>>>(row, col, gcur, sbinned, dbinned);
    binD1<<<NBINS, 256, 0, stream>>>(sbinned, offs, dinv);
    binD2<<<NBINS, 256, 0, stream>>>(dbinned, offs, dinv, cnt, endp, csr);
    embcvt<<<(N_NODES * NF) / 1024, 256, 0, stream>>>(emb, emb_bf);
    packW<<<8, 256, 0, stream>>>(W1_0, W1_1, W2_0, W2_1, pk);

    cheb_layer<<<LB2, 512, 0, stream>>>(emb_bf, csr, endp, cnt, pk, b1, h_bf, nullptr, 0);
    cheb_layer<<<LB2, 512, 0, stream>>>(h_bf, csr, endp, cnt, pk + 8192, b2, nullptr, out, 1);
}

// Round 7
// 251.146 us; speedup vs baseline: 1.3154x; 1.3154x over previous
//
#include <hip/hip_runtime.h>

#define N_NODES 100000
#define N_EDGES 1200000
#define NF 64

typedef __attribute__((ext_vector_type(8))) short short8;
typedef __attribute__((ext_vector_type(4))) float float4v;

__device__ __forceinline__ ushort f2bf(float f) {
    unsigned u = __float_as_uint(f);
    return (ushort)((u + 0x7FFF + ((u >> 16) & 1)) >> 16);  // RNE
}
__device__ __forceinline__ float bf2f(ushort b) {
    return __uint_as_float(((unsigned)b) << 16);
}

// binning: bin = node >> 9, 196 bins of 512 nodes
#define NBINS 196
#define EPB 5120
#define NBLK 235                  // ceil(1200000/5120)
#define CLEN (2 * NBINS * NBLK)   // 92120
#define SCAN_BLOCKS 360           // ceil(CLEN/256)

// ---------------- workspace layout (bytes), peak ~36.4 MB ----------------
#define OFF_DINV    0            // float[100000]
#define OFF_CNT     400128       // int[100000]
#define OFF_ENDP    800256       // int[100000]
#define OFF_BSUMS   1200384      // int[360]
#define OFF_PKW     1202048      // ushort[2*16*64*8] = 32 KB packed B-fragments
#define OFF_CSR     1235072      // int2[1200000] = 9.6 MB
#define OFF_SCRATCH 10835072
//   sbinned : SCRATCH + 0        int[1200000]  (4.8 MB)   } dead after binD1/D2
//   dbinned : SCRATCH + 4800000  int2[1200000] (9.6 MB)   }
//   counts  : SCRATCH + 14400000 int[CLEN]
//   offs    : SCRATCH + 14800000 int[CLEN]
//   emb_bf  : SCRATCH + 0        ushort[6.4M] (12.8 MB)   } after binD2
//   h_bf    : SCRATCH + 12800000 ushort[6.4M] (12.8 MB)   }

// Phase A: per-block LDS histograms by src-bin and dst-bin
__global__ __launch_bounds__(256) void binA(const int* __restrict__ row,
                                            const int* __restrict__ col,
                                            int* __restrict__ counts) {
    __shared__ int sh[NBINS], dh[NBINS];
    int t = threadIdx.x;
    if (t < NBINS) { sh[t] = 0; dh[t] = 0; }
    __syncthreads();
    int base = blockIdx.x * EPB;
    for (int k = 0; k < 20; ++k) {
        int e = base + k * 256 + t;
        if (e < N_EDGES) {
            int s = row[e], d = col[e];
            if (s != d) {
                atomicAdd(&sh[s >> 9], 1);
                atomicAdd(&dh[d >> 9], 1);
            }
        }
    }
    __syncthreads();
    if (t < NBINS) {
        counts[t * NBLK + blockIdx.x] = sh[t];
        counts[(NBINS + t) * NBLK + blockIdx.x] = dh[t];
    }
}

__global__ __launch_bounds__(256) void scanA(const int* __restrict__ in,
                                             int* __restrict__ out,
                                             int* __restrict__ bsums) {
    __shared__ int s[256];
    int t = threadIdx.x, i = blockIdx.x * 256 + t;
    int v = (i < CLEN) ? in[i] : 0;
    s[t] = v;
    __syncthreads();
    for (int off = 1; off < 256; off <<= 1) {
        int a = (t >= off) ? s[t - off] : 0;
        __syncthreads();
        s[t] += a;
        __syncthreads();
    }
    if (i < CLEN) out[i] = s[t] - v;
    if (t == 255) bsums[blockIdx.x] = s[255];
}

__global__ __launch_bounds__(512) void scanB(int* __restrict__ bsums) {
    __shared__ int s[512];
    int t = threadIdx.x;
    int v = (t < SCAN_BLOCKS) ? bsums[t] : 0;
    s[t] = v;
    __syncthreads();
    for (int off = 1; off < 512; off <<= 1) {
        int a = (t >= off) ? s[t - off] : 0;
        __syncthreads();
        s[t] += a;
        __syncthreads();
    }
    if (t < SCAN_BLOCKS) bsums[t] = s[t] - v;
}

__global__ __launch_bounds__(256) void scanC(int* __restrict__ out,
                                             const int* __restrict__ bsums) {
    int i = blockIdx.x * 256 + threadIdx.x;
    if (i < CLEN) out[i] += bsums[blockIdx.x];
}

// Phase C: place edges into binned arrays via per-block LDS cursors
__global__ __launch_bounds__(256) void binC(const int* __restrict__ row,
                                            const int* __restrict__ col,
                                            const int* __restrict__ offs,
                                            int* __restrict__ sbinned,
                                            int2* __restrict__ dbinned) {
    __shared__ int cur[2 * NBINS];
    int t = threadIdx.x;
    for (int i = t; i < 2 * NBINS; i += 256) cur[i] = offs[i * NBLK + blockIdx.x];
    __syncthreads();
    int E1 = offs[NBINS * NBLK];
    int base = blockIdx.x * EPB;
    for (int k = 0; k < 20; ++k) {
        int e = base + k * 256 + t;
        if (e < N_EDGES) {
            int s = row[e], d = col[e];
            if (s != d) {
                int ss = atomicAdd(&cur[s >> 9], 1);
                sbinned[ss] = s;
                int ds = atomicAdd(&cur[NBINS + (d >> 9)], 1);
                dbinned[ds - E1] = make_int2(s, d);
            }
        }
    }
}

// Phase D1: per src-bin per-node histogram -> dinv
__global__ __launch_bounds__(256) void binD1(const int* __restrict__ sbinned,
                                             const int* __restrict__ offs,
                                             float* __restrict__ dinv) {
    __shared__ int hist[512];
    int t = threadIdx.x;
    hist[t] = 0; hist[t + 256] = 0;
    __syncthreads();
    int b = blockIdx.x;
    int E1 = offs[NBINS * NBLK];
    int start = offs[b * NBLK];
    int end = (b == NBINS - 1) ? E1 : offs[(b + 1) * NBLK];
    for (int i = start + t; i < end; i += 256)
        atomicAdd(&hist[sbinned[i] - (b << 9)], 1);
    __syncthreads();
    int n0 = (b << 9) + t, n1 = n0 + 256;
    if (n0 < N_NODES) dinv[n0] = hist[t] ? rsqrtf((float)hist[t]) : 0.0f;
    if (n1 < N_NODES) dinv[n1] = hist[t + 256] ? rsqrtf((float)hist[t + 256]) : 0.0f;
}

// Phase D2: per dst-bin histogram + LDS scan -> cnt/endp + CSR placement
__global__ __launch_bounds__(256) void binD2(const int2* __restrict__ dbinned,
                                             const int* __restrict__ offs,
                                             const float* __restrict__ dinv,
                                             int* __restrict__ cnt,
                                             int* __restrict__ endp,
                                             int2* __restrict__ csr) {
    __shared__ int hist[512];
    __shared__ int lcur[512];
    int t = threadIdx.x;
    hist[t] = 0; hist[t + 256] = 0;
    __syncthreads();
    int b = blockIdx.x;
    int E1 = offs[NBINS * NBLK];
    int start = offs[(NBINS + b) * NBLK] - E1;
    int end = (b == NBINS - 1) ? E1 : (offs[(NBINS + b + 1) * NBLK] - E1);
    for (int i = start + t; i < end; i += 256)
        atomicAdd(&hist[dbinned[i].y - (b << 9)], 1);
    __syncthreads();
    int o0 = hist[t], o1 = hist[t + 256];
    for (int off = 1; off < 512; off <<= 1) {
        int v0 = (t >= off) ? hist[t - off] : 0;
        int v1 = (t + 256 >= off) ? hist[t + 256 - off] : 0;
        __syncthreads();
        hist[t] += v0; hist[t + 256] += v1;
        __syncthreads();
    }
    int e0 = hist[t] - o0, e1 = hist[t + 256] - o1;
    lcur[t] = start + e0;
    lcur[t + 256] = start + e1;
    int n0 = (b << 9) + t, n1 = n0 + 256;
    if (n0 < N_NODES) { cnt[n0] = o0; endp[n0] = start + e0 + o0; }
    if (n1 < N_NODES) { cnt[n1] = o1; endp[n1] = start + e1 + o1; }
    __syncthreads();
    for (int i = start + t; i < end; i += 256) {
        int2 r = dbinned[i];
        int slot = atomicAdd(&lcur[r.y - (b << 9)], 1);
        float nrm = -dinv[r.x] * dinv[r.y];
        csr[slot] = make_int2(r.x, __float_as_int(nrm));
    }
}

// emb f32 -> bf16 (RNE)
__global__ __launch_bounds__(256) void embcvt(const float* __restrict__ in,
                                              ushort* __restrict__ out) {
    int i = (blockIdx.x * 256 + threadIdx.x) * 4;
    float4 v = *(const float4*)(in + i);
    ushort4 o;
    o.x = f2bf(v.x); o.y = f2bf(v.y); o.z = f2bf(v.z); o.w = f2bf(v.w);
    *(ushort4*)(out + i) = o;
}

// pack both layers' B=[W0;W1] (128x64 f32) into MFMA B-fragment order (bf16)
__global__ __launch_bounds__(256) void packW(const float* __restrict__ W10,
                                             const float* __restrict__ W11,
                                             const float* __restrict__ W20,
                                             const float* __restrict__ W21,
                                             ushort* __restrict__ pk) {
    int idx = blockIdx.x * 256 + threadIdx.x;   // [0, 2048)
    int layer = idx >> 10;
    int rest = idx & 1023;
    int f = rest >> 6, L = rest & 63;
    int n = (f & 3) * 16 + (L & 15);
    int kb = (f >> 2) * 32 + ((L >> 4) << 3);
#pragma unroll
    for (int j = 0; j < 8; ++j) {
        int k = kb + j;
        const float* W = layer ? ((k < 64) ? W20 : W21) : ((k < 64) ? W10 : W11);
        float v = W[(k & 63) * 64 + n];
        pk[idx * 8 + j] = f2bf(v);
    }
}

// Fused layer: 16 nodes/wave aggregation (bf16 gather, pipelined csr) + MFMA.
#define NPW 16
#define WPB 8
#define NPB (NPW * WPB)                       // 128
#define LB2 ((N_NODES + NPB - 1) / NPB)       // 782

__global__ __launch_bounds__(512, 7) void cheb_layer(const ushort* __restrict__ x,
                                                     const int2* __restrict__ csr,
                                                     const int* __restrict__ endp,
                                                     const int* __restrict__ cnt,
                                                     const ushort* __restrict__ pk,
                                                     const float* __restrict__ bias,
                                                     ushort* __restrict__ out_bf,
                                                     float* __restrict__ out_f32,
                                                     int last) {
    __shared__ ushort sA[WPB][16][136];   // 34.8 KB

    int t = threadIdx.x;
    int lane = t & 63, wid = t >> 6;
    int c = lane & 15, q = lane >> 4;
    int nb = blockIdx.x * NPB + wid * NPW;

    int nend = 0, ncnt = 0;
    if (lane < NPW && nb + lane < N_NODES) {
        nend = endp[nb + lane];
        ncnt = cnt[nb + lane];
    }

    for (int g = 0; g < NPW; ++g) {
        int node = nb + g;
        int cn = __builtin_amdgcn_readlane(ncnt, g);
        int eend = __builtin_amdgcn_readlane(nend, g);
        int e = eend - cn;
        ushort xb = (node < N_NODES) ? x[(size_t)node * NF + lane] : (ushort)0;
        float a0 = 0, a1 = 0, a2 = 0, a3 = 0, a4 = 0, a5 = 0, a6 = 0, a7 = 0;
        int full = cn >> 3;
        if (full) {
            int2 q0 = csr[e + 0], q1 = csr[e + 1], q2 = csr[e + 2], q3 = csr[e + 3];
            int2 q4 = csr[e + 4], q5 = csr[e + 5], q6 = csr[e + 6], q7 = csr[e + 7];
            for (int it = 1; it < full; ++it) {
                float g0 = bf2f(x[(size_t)q0.x * NF + lane]);
                float g1 = bf2f(x[(size_t)q1.x * NF + lane]);
                float g2 = bf2f(x[(size_t)q2.x * NF + lane]);
                float g3 = bf2f(x[(size_t)q3.x * NF + lane]);
                float g4 = bf2f(x[(size_t)q4.x * NF + lane]);
                float g5 = bf2f(x[(size_t)q5.x * NF + lane]);
                float g6 = bf2f(x[(size_t)q6.x * NF + lane]);
                float g7 = bf2f(x[(size_t)q7.x * NF + lane]);
                int2 r0 = csr[e + 8],  r1 = csr[e + 9],  r2 = csr[e + 10], r3 = csr[e + 11];
                int2 r4 = csr[e + 12], r5 = csr[e + 13], r6 = csr[e + 14], r7 = csr[e + 15];
                a0 = fmaf(__int_as_float(q0.y), g0, a0);
                a1 = fmaf(__int_as_float(q1.y), g1, a1);
                a2 = fmaf(__int_as_float(q2.y), g2, a2);
                a3 = fmaf(__int_as_float(q3.y), g3, a3);
                a4 = fmaf(__int_as_float(q4.y), g4, a4);
                a5 = fmaf(__int_as_float(q5.y), g5, a5);
                a6 = fmaf(__int_as_float(q6.y), g6, a6);
                a7 = fmaf(__int_as_float(q7.y), g7, a7);
                q0 = r0; q1 = r1; q2 = r2; q3 = r3;
                q4 = r4; q5 = r5; q6 = r6; q7 = r7;
                e += 8;
            }
            a0 = fmaf(__int_as_float(q0.y), bf2f(x[(size_t)q0.x * NF + lane]), a0);
            a1 = fmaf(__int_as_float(q1.y), bf2f(x[(size_t)q1.x * NF + lane]), a1);
            a2 = fmaf(__int_as_float(q2.y), bf2f(x[(size_t)q2.x * NF + lane]), a2);
            a3 = fmaf(__int_as_float(q3.y), bf2f(x[(size_t)q3.x * NF + lane]), a3);
            a4 = fmaf(__int_as_float(q4.y), bf2f(x[(size_t)q4.x * NF + lane]), a4);
            a5 = fmaf(__int_as_float(q5.y), bf2f(x[(size_t)q5.x * NF + lane]), a5);
            a6 = fmaf(__int_as_float(q6.y), bf2f(x[(size_t)q6.x * NF + lane]), a6);
            a7 = fmaf(__int_as_float(q7.y), bf2f(x[(size_t)q7.x * NF + lane]), a7);
            e += 8;
        }
        for (; e < eend; ++e) {
            int2 p = csr[e];
            a0 = fmaf(__int_as_float(p.y), bf2f(x[(size_t)p.x * NF + lane]), a0);
        }
        float acc = ((a0 + a1) + (a2 + a3)) + ((a4 + a5) + (a6 + a7));
        sA[wid][g][lane] = xb;
        sA[wid][g][64 + lane] = f2bf(acc);
    }
    __builtin_amdgcn_wave_barrier();

    const short8* pk8 = (const short8*)pk;
    float4v C[4];
#pragma unroll
    for (int nt = 0; nt < 4; ++nt) {
        float b = bias[nt * 16 + c];
        C[nt] = (float4v){b, b, b, b};
    }
#pragma unroll
    for (int kt = 0; kt < 4; ++kt) {
        short8 af = *(const short8*)&sA[wid][c][kt * 32 + q * 8];
#pragma unroll
        for (int nt = 0; nt < 4; ++nt) {
            short8 bfr = pk8[(kt * 4 + nt) * 64 + lane];
            C[nt] = __builtin_amdgcn_mfma_f32_16x16x32_bf16(af, bfr, C[nt], 0, 0, 0);
        }
    }

#pragma unroll
    for (int nt = 0; nt < 4; ++nt) {
#pragma unroll
        for (int i = 0; i < 4; ++i) {
            int node = nb + q * 4 + i;
            if (node < N_NODES) {
                float v = C[nt][i];
                if (!last) {
                    v = fmaxf(v, 0.0f);
                    out_bf[(size_t)node * NF + nt * 16 + c] = f2bf(v);
                } else {
                    out_f32[(size_t)node * NF + nt * 16 + c] = v;
                }
            }
        }
    }
}

extern "C" void kernel_launch(void* const* d_in, const int* in_sizes, int n_in,
                              void* d_out, int out_size, void* d_ws, size_t ws_size,
                              hipStream_t stream) {
    const int* ei = (const int*)d_in[0];
    const int* row = ei;
    const int* col = ei + N_EDGES;
    const float* emb = (const float*)d_in[1];
    const float* W1_0 = (const float*)d_in[2];
    const float* W1_1 = (const float*)d_in[3];
    const float* b1 = (const float*)d_in[4];
    const float* W2_0 = (const float*)d_in[5];
    const float* W2_1 = (const float*)d_in[6];
    const float* b2 = (const float*)d_in[7];
    float* out = (float*)d_out;

    char* ws = (char*)d_ws;
    float* dinv = (float*)(ws + OFF_DINV);
    int* cnt = (int*)(ws + OFF_CNT);
    int* endp = (int*)(ws + OFF_ENDP);
    int* bsums = (int*)(ws + OFF_BSUMS);
    ushort* pk = (ushort*)(ws + OFF_PKW);
    int2* csr = (int2*)(ws + OFF_CSR);
    char* scratch = ws + OFF_SCRATCH;
    int* sbinned = (int*)(scratch);
    int2* dbinned = (int2*)(scratch + 4800000);
    int* counts = (int*)(scratch + 14400000);
    int* offs = (int*)(scratch + 14800000);
    ushort* emb_bf = (ushort*)(scratch);              // after binD1/binD2
    ushort* h_bf = (ushort*)(scratch + 12800000);     // after binD2

    binA<<<NBLK, 256, 0, stream>>>(row, col, counts);
    scanA<<<SCAN_BLOCKS, 256, 0, stream>>>(counts, offs, bsums);
    scanB<<<1, 512, 0, stream>>>(bsums);
    scanC<<<SCAN_BLOCKS, 256, 0, stream>>>(offs, bsums);
    binC<<<NBLK, 256, 0, stream>>>(row, col, offs, sbinned, dbinned);
    binD1<<<NBINS, 256, 0, stream>>>(sbinned, offs, dinv);
    binD2<<<NBINS, 256, 0, stream>>>(dbinned, offs, dinv, cnt, endp, csr);
    embcvt<<<(N_NODES * NF) / 1024, 256, 0, stream>>>(emb, emb_bf);
    packW<<<8, 256, 0, stream>>>(W1_0, W1_1, W2_0, W2_1, pk);

    cheb_layer<<<LB2, 512, 0, stream>>>(emb_bf, csr, endp, cnt, pk, b1, h_bf, nullptr, 0);
    cheb_layer<<<LB2, 512, 0, stream>>>(h_bf, csr, endp, cnt, pk + 8192, b2, nullptr, out, 1);
}

// Round 9
// 236.041 us; speedup vs baseline: 1.3996x; 1.0640x over previous
//
#include <hip/hip_runtime.h>

#define N_NODES 100000
#define N_EDGES 1200000
#define NF 64

typedef __attribute__((ext_vector_type(8))) short short8;
typedef __attribute__((ext_vector_type(4))) float float4v;

__device__ __forceinline__ ushort f2bf(float f) {
    unsigned u = __float_as_uint(f);
    return (ushort)((u + 0x7FFF + ((u >> 16) & 1)) >> 16);  // RNE
}

// binning: bin = node >> 9, 196 bins of 512 nodes, fixed capacity per bin
#define NBINS 196
#define CAP 7680                 // mean 6144, sigma ~78; aligned total <= ~7400
#define EPB 5120
#define NBLK 235                 // ceil(1200000/5120)

// ---------------- workspace layout (bytes), peak 35.87 MB ----------------
#define OFF_CNT    0             // int[100000]
#define OFF_ENDP   400128        // int[100000]
#define OFF_DINV   800256        // float[100000] (dead after binD2)
#define OFF_CUR    1200384       // int[392] global bin cursors
#define OFF_PKW    1202048       // ushort[2*1024*8] = 32 KB packed B-fragments
#define OFF_SRCS   1234816       // int[196*7680]   = 6.02 MB (final, dst-binned)
#define OFF_NRMS   7255936       // ushort[196*7680] = 3.01 MB
#define OFF_SBIN   10266496      // int[196*7680]  (staging, dead after binD1)
#define OFF_DBIN   16287616      // int2[196*7680] (staging, dead after binD2)
#define OFF_EMBBF  10266496      // ushort[6.4M] 12.8 MB (overlays SBIN/DBIN, after binD2)
#define OFF_HBF    23066496      // ushort[6.4M] 12.8 MB -> ends 35,866,496

// pack both layers' B=[W0;W1] into MFMA B-fragment order; block 8 inits cursors
__global__ __launch_bounds__(256) void packW(const float* __restrict__ W10,
                                             const float* __restrict__ W11,
                                             const float* __restrict__ W20,
                                             const float* __restrict__ W21,
                                             ushort* __restrict__ pk,
                                             int* __restrict__ cur) {
    if (blockIdx.x == 8) {
        // FIX (r8 crash): strided loop — 256 threads must cover all 392 cursors;
        // the r8 guard `if (t < 392)` left cur[256..391] poisoned (0xAA) -> wild
        // dbinned scatter -> GPU memory fault.
        for (int i = threadIdx.x; i < 2 * NBINS; i += 256)
            cur[i] = (i < NBINS ? i : i - NBINS) * CAP;
        return;
    }
    int idx = blockIdx.x * 256 + threadIdx.x;   // [0, 2048)
    int layer = idx >> 10;
    int rest = idx & 1023;
    int f = rest >> 6, L = rest & 63;
    int n = (f & 3) * 16 + (L & 15);
    int kb = (f >> 2) * 32 + ((L >> 4) << 3);
#pragma unroll
    for (int j = 0; j < 8; ++j) {
        int k = kb + j;
        const float* W = layer ? ((k < 64) ? W20 : W21) : ((k < 64) ? W10 : W11);
        pk[idx * 8 + j] = f2bf(W[(k & 63) * 64 + n]);
    }
}

// single-pass binned counting sort: LDS hist -> chunk reservation -> scatter
__global__ __launch_bounds__(256) void binsort(const int* __restrict__ row,
                                               const int* __restrict__ col,
                                               int* __restrict__ cur,
                                               int* __restrict__ sbinned,
                                               int2* __restrict__ dbinned) {
    __shared__ int sh[NBINS], dh[NBINS];
    __shared__ int sbase[NBINS], dbase[NBINS];
    int t = threadIdx.x;
    if (t < NBINS) { sh[t] = 0; dh[t] = 0; }
    __syncthreads();
    int base = blockIdx.x * EPB;
    for (int k = 0; k < 20; ++k) {
        int e = base + k * 256 + t;
        if (e < N_EDGES) {
            int s = row[e], d = col[e];
            if (s != d) {
                atomicAdd(&sh[s >> 9], 1);
                atomicAdd(&dh[d >> 9], 1);
            }
        }
    }
    __syncthreads();
    if (t < NBINS) {
        sbase[t] = atomicAdd(&cur[t], sh[t]);
        dbase[t] = atomicAdd(&cur[NBINS + t], dh[t]);
    }
    __syncthreads();
    for (int k = 0; k < 20; ++k) {
        int e = base + k * 256 + t;
        if (e < N_EDGES) {
            int s = row[e], d = col[e];
            if (s != d) {
                int ss = atomicAdd(&sbase[s >> 9], 1);
                sbinned[ss] = s;
                int ds = atomicAdd(&dbase[d >> 9], 1);
                dbinned[ds] = make_int2(s, d);
            }
        }
    }
}

// per src-bin per-node histogram -> dinv
__global__ __launch_bounds__(256) void binD1(const int* __restrict__ sbinned,
                                             const int* __restrict__ cur,
                                             float* __restrict__ dinv) {
    __shared__ int hist[512];
    int t = threadIdx.x;
    hist[t] = 0; hist[t + 256] = 0;
    __syncthreads();
    int b = blockIdx.x;
    int start = b * CAP;
    int end = cur[b];
    for (int i = start + t; i < end; i += 256)
        atomicAdd(&hist[sbinned[i] - (b << 9)], 1);
    __syncthreads();
    int n0 = (b << 9) + t, n1 = n0 + 256;
    if (n0 < N_NODES) dinv[n0] = hist[t] ? rsqrtf((float)hist[t]) : 0.0f;
    if (n1 < N_NODES) dinv[n1] = hist[t + 256] ? rsqrtf((float)hist[t + 256]) : 0.0f;
}

// per dst-bin: hist + scan of 4-aligned counts -> cnt/endp + srcs/nrms scatter
__global__ __launch_bounds__(256) void binD2(const int2* __restrict__ dbinned,
                                             const int* __restrict__ cur,
                                             const float* __restrict__ dinv,
                                             int* __restrict__ cnt,
                                             int* __restrict__ endp,
                                             int* __restrict__ srcs,
                                             ushort* __restrict__ nrms) {
    __shared__ int hist[512];
    __shared__ int lcur[512];
    __shared__ int tot_s;
    int t = threadIdx.x;
    hist[t] = 0; hist[t + 256] = 0;
    __syncthreads();
    int b = blockIdx.x;
    int start = b * CAP;
    int end = cur[NBINS + b];
    for (int i = start + t; i < end; i += 256)
        atomicAdd(&hist[dbinned[i].y - (b << 9)], 1);
    __syncthreads();
    int o0 = hist[t], o1 = hist[t + 256];
    int A0 = (o0 + 3) & ~3, A1 = (o1 + 3) & ~3;
    __syncthreads();
    hist[t] = A0; hist[t + 256] = A1;
    __syncthreads();
    for (int off = 1; off < 512; off <<= 1) {
        int v0 = (t >= off) ? hist[t - off] : 0;
        int v1 = (t + 256 >= off) ? hist[t + 256 - off] : 0;
        __syncthreads();
        hist[t] += v0; hist[t + 256] += v1;
        __syncthreads();
    }
    int e0 = hist[t] - A0, e1 = hist[t + 256] - A1;   // exclusive (aligned)
    if (t == 255) tot_s = hist[511];
    lcur[t] = start + e0;
    lcur[t + 256] = start + e1;
    int n0 = (b << 9) + t, n1 = n0 + 256;
    if (n0 < N_NODES) { cnt[n0] = o0; endp[n0] = start + e0 + o0; }
    if (n1 < N_NODES) { cnt[n1] = o1; endp[n1] = start + e1 + o1; }
    __syncthreads();
    for (int i = start + t; i < end; i += 256) {
        int2 r = dbinned[i];
        int slot = atomicAdd(&lcur[r.y - (b << 9)], 1);
        srcs[slot] = r.x;
        nrms[slot] = f2bf(-dinv[r.x] * dinv[r.y]);
    }
    __syncthreads();
    // zero-fill per-node alignment pads
    for (int k = o0; k < A0; ++k) { srcs[start + e0 + k] = 0; nrms[start + e0 + k] = 0; }
    for (int k = o1; k < A1; ++k) { srcs[start + e1 + k] = 0; nrms[start + e1 + k] = 0; }
    // zero-fill 8-slot bin tail (layer's 8-chunk loop may overrun by <=7)
    if (t < 8) { srcs[start + tot_s + t] = 0; nrms[start + tot_s + t] = 0; }
}

// emb f32 -> bf16 (RNE), 8 elems/thread
__global__ __launch_bounds__(256) void embcvt(const float* __restrict__ in,
                                              ushort* __restrict__ out) {
    int i = (blockIdx.x * 256 + threadIdx.x) * 8;
    float4 v0 = *(const float4*)(in + i);
    float4 v1 = *(const float4*)(in + i + 4);
    uint4 o;
    o.x = (uint)f2bf(v0.x) | ((uint)f2bf(v0.y) << 16);
    o.y = (uint)f2bf(v0.z) | ((uint)f2bf(v0.w) << 16);
    o.z = (uint)f2bf(v1.x) | ((uint)f2bf(v1.y) << 16);
    o.w = (uint)f2bf(v1.z) | ((uint)f2bf(v1.w) << 16);
    *(uint4*)(out + i) = o;
}

// Fused layer: 16 nodes/wave; gather 4 edges per instruction (quarter-wave per
// edge, 4 features/lane), cross-quarter shfl_xor reduce, then MFMA GEMM.
#define NPW 16
#define WPB 8
#define NPB (NPW * WPB)                       // 128
#define LB2 ((N_NODES + NPB - 1) / NPB)       // 782

__global__ __launch_bounds__(512, 7) void cheb_layer(const ushort* __restrict__ x,
                                                     const int* __restrict__ srcs,
                                                     const ushort* __restrict__ nrms,
                                                     const int* __restrict__ endp,
                                                     const int* __restrict__ cnt,
                                                     const ushort* __restrict__ pk,
                                                     const float* __restrict__ bias,
                                                     ushort* __restrict__ out_bf,
                                                     float* __restrict__ out_f32,
                                                     int last) {
    __shared__ ushort sA[WPB][16][136];   // 34.8 KB

    int t = threadIdx.x;
    int lane = t & 63, wid = t >> 6;
    int c = lane & 15, q = lane >> 4;
    int qd = q, fg = c;
    int nb = blockIdx.x * NPB + wid * NPW;

    int nend = 0, ncnt = 0;
    if (lane < NPW && nb + lane < N_NODES) {
        nend = endp[nb + lane];
        ncnt = cnt[nb + lane];
    }

    const uint2* xr = (const uint2*)x;   // row = 16 uint2 (64 bf16)

    for (int g = 0; g < NPW; ++g) {
        int node = nb + g;
        int cn = __builtin_amdgcn_readlane(ncnt, g);
        int eend = __builtin_amdgcn_readlane(nend, g);
        int e = eend - cn;               // 4-aligned segment start
        float a0 = 0, a1 = 0, a2 = 0, a3 = 0;
        for (; e < eend; e += 8) {
            int4 sv = *(const int4*)(srcs + e);       // edges e..e+3 (uniform)
            int4 sw = *(const int4*)(srcs + e + 4);   // edges e+4..e+7
            uint2 nv = *(const uint2*)(nrms + e);     // 4 bf16 norms
            uint2 nw = *(const uint2*)(nrms + e + 4);
            int sA01 = (qd & 1) ? sv.y : sv.x;
            int sA23 = (qd & 1) ? sv.w : sv.z;
            int srcA = (qd & 2) ? sA23 : sA01;
            int sB01 = (qd & 1) ? sw.y : sw.x;
            int sB23 = (qd & 1) ? sw.w : sw.z;
            int srcB = (qd & 2) ? sB23 : sB01;
            uint nAp = (qd & 2) ? nv.y : nv.x;
            uint nBp = (qd & 2) ? nw.y : nw.x;
            float nAf = __uint_as_float((qd & 1) ? (nAp & 0xffff0000u) : (nAp << 16));
            float nBf = __uint_as_float((qd & 1) ? (nBp & 0xffff0000u) : (nBp << 16));
            nAf = (e + qd < eend) ? nAf : 0.0f;
            nBf = (e + 4 + qd < eend) ? nBf : 0.0f;
            uint2 gA = xr[(size_t)srcA * 16 + fg];
            uint2 gB = xr[(size_t)srcB * 16 + fg];
            a0 = fmaf(nAf, __uint_as_float(gA.x << 16), a0);
            a1 = fmaf(nAf, __uint_as_float(gA.x & 0xffff0000u), a1);
            a2 = fmaf(nAf, __uint_as_float(gA.y << 16), a2);
            a3 = fmaf(nAf, __uint_as_float(gA.y & 0xffff0000u), a3);
            a0 = fmaf(nBf, __uint_as_float(gB.x << 16), a0);
            a1 = fmaf(nBf, __uint_as_float(gB.x & 0xffff0000u), a1);
            a2 = fmaf(nBf, __uint_as_float(gB.y << 16), a2);
            a3 = fmaf(nBf, __uint_as_float(gB.y & 0xffff0000u), a3);
        }
        // sum the 4 quarter-wave partials (each holds same fg, different edges)
        a0 += __shfl_xor(a0, 16, 64); a1 += __shfl_xor(a1, 16, 64);
        a2 += __shfl_xor(a2, 16, 64); a3 += __shfl_xor(a3, 16, 64);
        a0 += __shfl_xor(a0, 32, 64); a1 += __shfl_xor(a1, 32, 64);
        a2 += __shfl_xor(a2, 32, 64); a3 += __shfl_xor(a3, 32, 64);
        int nidx = (node < N_NODES) ? node : 0;
        if (qd == 0) {
            uint2 xv = xr[(size_t)nidx * 16 + fg];
            *(uint2*)&sA[wid][g][4 * fg] = xv;
        }
        if (qd == 1) {
            uint2 p;
            p.x = (uint)f2bf(a0) | ((uint)f2bf(a1) << 16);
            p.y = (uint)f2bf(a2) | ((uint)f2bf(a3) << 16);
            *(uint2*)&sA[wid][g][64 + 4 * fg] = p;
        }
    }
    __builtin_amdgcn_wave_barrier();

    const short8* pk8 = (const short8*)pk;
    float4v C[4];
#pragma unroll
    for (int nt = 0; nt < 4; ++nt) {
        float b = bias[nt * 16 + c];
        C[nt] = (float4v){b, b, b, b};
    }
#pragma unroll
    for (int kt = 0; kt < 4; ++kt) {
        short8 af = *(const short8*)&sA[wid][c][kt * 32 + q * 8];
#pragma unroll
        for (int nt = 0; nt < 4; ++nt) {
            short8 bfr = pk8[(kt * 4 + nt) * 64 + lane];
            C[nt] = __builtin_amdgcn_mfma_f32_16x16x32_bf16(af, bfr, C[nt], 0, 0, 0);
        }
    }

#pragma unroll
    for (int nt = 0; nt < 4; ++nt) {
#pragma unroll
        for (int i = 0; i < 4; ++i) {
            int node = nb + q * 4 + i;
            if (node < N_NODES) {
                float v = C[nt][i];
                if (!last) {
                    v = fmaxf(v, 0.0f);
                    out_bf[(size_t)node * NF + nt * 16 + c] = f2bf(v);
                } else {
                    out_f32[(size_t)node * NF + nt * 16 + c] = v;
                }
            }
        }
    }
}

extern "C" void kernel_launch(void* const* d_in, const int* in_sizes, int n_in,
                              void* d_out, int out_size, void* d_ws, size_t ws_size,
                              hipStream_t stream) {
    const int* ei = (const int*)d_in[0];
    const int* row = ei;
    const int* col = ei + N_EDGES;
    const float* emb = (const float*)d_in[1];
    const float* W1_0 = (const float*)d_in[2];
    const float* W1_1 = (const float*)d_in[3];
    const float* b1 = (const float*)d_in[4];
    const float* W2_0 = (const float*)d_in[5];
    const float* W2_1 = (const float*)d_in[6];
    const float* b2 = (const float*)d_in[7];
    float* out = (float*)d_out;

    char* ws = (char*)d_ws;
    int* cnt = (int*)(ws + OFF_CNT);
    int* endp = (int*)(ws + OFF_ENDP);
    float* dinv = (float*)(ws + OFF_DINV);
    int* cur = (int*)(ws + OFF_CUR);
    ushort* pk = (ushort*)(ws + OFF_PKW);
    int* srcs = (int*)(ws + OFF_SRCS);
    ushort* nrms = (ushort*)(ws + OFF_NRMS);
    int* sbinned = (int*)(ws + OFF_SBIN);
    int2* dbinned = (int2*)(ws + OFF_DBIN);
    ushort* emb_bf = (ushort*)(ws + OFF_EMBBF);   // after binD2
    ushort* h_bf = (ushort*)(ws + OFF_HBF);

    packW<<<9, 256, 0, stream>>>(W1_0, W1_1, W2_0, W2_1, pk, cur);
    binsort<<<NBLK, 256, 0, stream>>>(row, col, cur, sbinned, dbinned);
    binD1<<<NBINS, 256, 0, stream>>>(sbinned, cur, dinv);
    binD2<<<NBINS, 256, 0, stream>>>(dbinned, cur, dinv, cnt, endp, srcs, nrms);
    embcvt<<<(N_NODES * NF) / 2048, 256, 0, stream>>>(emb, emb_bf);

    cheb_layer<<<LB2, 512, 0, stream>>>(emb_bf, srcs, nrms, endp, cnt, pk, b1, h_bf, nullptr, 0);
    cheb_layer<<<LB2, 512, 0, stream>>>(h_bf, srcs, nrms, endp, cnt, pk + 8192, b2, nullptr, out, 1);
}

// Round 10
// 231.170 us; speedup vs baseline: 1.4291x; 1.0211x over previous
//
#include <hip/hip_runtime.h>

#define N_NODES 100000
#define N_EDGES 1200000
#define NF 64

typedef __attribute__((ext_vector_type(8))) short short8;
typedef __attribute__((ext_vector_type(4))) float float4v;

__device__ __forceinline__ ushort f2bf(float f) {
    unsigned u = __float_as_uint(f);
    return (ushort)((u + 0x7FFF + ((u >> 16) & 1)) >> 16);  // RNE
}

// binning: bin = node >> 9, 196 bins of 512 nodes, fixed capacity per bin
#define NBINS 196
#define CAP 7680                 // mean 6144, sigma ~78; aligned total <= ~7400
#define EPB 5120
#define NBLK 235                 // ceil(1200000/5120)

// ---------------- workspace layout (bytes), peak ~35.9 MB ----------------
#define OFF_CNT    0             // int[100000]
#define OFF_ENDP   400128        // int[100000]
#define OFF_DINV   800256        // float[100000] (dead after binD2)
#define OFF_CUR    1200384       // int[392] global bin cursors
#define OFF_PKW    1202048       // ushort[2*1024*8] = 32 KB packed B-fragments
#define OFF_SRCS   1234816       // int[196*7680]   = 6.02 MB (final, dst-binned)
#define OFF_NRMS   7255936       // ushort[196*7680] = 3.01 MB
#define OFF_SBIN   10266496      // ushort[196*7680] 3.01 MB (staging, dead after binD1)
#define OFF_DBIN   16287616      // int[196*7680]    6.02 MB (staging, dead after binD2)
#define OFF_EMBBF  10266496      // ushort[6.4M] 12.8 MB (overlays SBIN/DBIN, after binD2)
#define OFF_HBF    23066496      // ushort[6.4M] 12.8 MB -> ends 35,866,496

// pack both layers' B=[W0;W1] into MFMA B-fragment order; block 8 inits cursors
__global__ __launch_bounds__(256) void packW(const float* __restrict__ W10,
                                             const float* __restrict__ W11,
                                             const float* __restrict__ W20,
                                             const float* __restrict__ W21,
                                             ushort* __restrict__ pk,
                                             int* __restrict__ cur) {
    if (blockIdx.x == 8) {
        for (int i = threadIdx.x; i < 2 * NBINS; i += 256)
            cur[i] = (i < NBINS ? i : i - NBINS) * CAP;
        return;
    }
    int idx = blockIdx.x * 256 + threadIdx.x;   // [0, 2048)
    int layer = idx >> 10;
    int rest = idx & 1023;
    int f = rest >> 6, L = rest & 63;
    int n = (f & 3) * 16 + (L & 15);
    int kb = (f >> 2) * 32 + ((L >> 4) << 3);
#pragma unroll
    for (int j = 0; j < 8; ++j) {
        int k = kb + j;
        const float* W = layer ? ((k < 64) ? W20 : W21) : ((k < 64) ? W10 : W11);
        pk[idx * 8 + j] = f2bf(W[(k & 63) * 64 + n]);
    }
}

// single-pass binned counting sort: LDS hist -> chunk reservation -> scatter.
// sbinned stores 2-byte local ids; dbinned packs (s<<9)|dlocal in one int.
__global__ __launch_bounds__(256) void binsort(const int* __restrict__ row,
                                               const int* __restrict__ col,
                                               int* __restrict__ cur,
                                               ushort* __restrict__ sbinned,
                                               int* __restrict__ dbinned) {
    __shared__ int sh[NBINS], dh[NBINS];
    __shared__ int sbase[NBINS], dbase[NBINS];
    int t = threadIdx.x;
    if (t < NBINS) { sh[t] = 0; dh[t] = 0; }
    __syncthreads();
    int base = blockIdx.x * EPB;
    for (int k = 0; k < 20; ++k) {
        int e = base + k * 256 + t;
        if (e < N_EDGES) {
            int s = row[e], d = col[e];
            if (s != d) {
                atomicAdd(&sh[s >> 9], 1);
                atomicAdd(&dh[d >> 9], 1);
            }
        }
    }
    __syncthreads();
    if (t < NBINS) {
        sbase[t] = atomicAdd(&cur[t], sh[t]);
        dbase[t] = atomicAdd(&cur[NBINS + t], dh[t]);
    }
    __syncthreads();
    for (int k = 0; k < 20; ++k) {
        int e = base + k * 256 + t;
        if (e < N_EDGES) {
            int s = row[e], d = col[e];
            if (s != d) {
                int ss = atomicAdd(&sbase[s >> 9], 1);
                sbinned[ss] = (ushort)(s & 511);
                int ds = atomicAdd(&dbase[d >> 9], 1);
                dbinned[ds] = (s << 9) | (d & 511);
            }
        }
    }
}

// per src-bin per-node histogram -> dinv
__global__ __launch_bounds__(256) void binD1(const ushort* __restrict__ sbinned,
                                             const int* __restrict__ cur,
                                             float* __restrict__ dinv) {
    __shared__ int hist[512];
    int t = threadIdx.x;
    hist[t] = 0; hist[t + 256] = 0;
    __syncthreads();
    int b = blockIdx.x;
    int start = b * CAP;
    int end = cur[b];
    for (int i = start + t; i < end; i += 256)
        atomicAdd(&hist[sbinned[i]], 1);
    __syncthreads();
    int n0 = (b << 9) + t, n1 = n0 + 256;
    if (n0 < N_NODES) dinv[n0] = hist[t] ? rsqrtf((float)hist[t]) : 0.0f;
    if (n1 < N_NODES) dinv[n1] = hist[t + 256] ? rsqrtf((float)hist[t + 256]) : 0.0f;
}

// per dst-bin: hist + scan of 4-aligned counts -> cnt/endp + srcs/nrms scatter
__global__ __launch_bounds__(256) void binD2(const int* __restrict__ dbinned,
                                             const int* __restrict__ cur,
                                             const float* __restrict__ dinv,
                                             int* __restrict__ cnt,
                                             int* __restrict__ endp,
                                             int* __restrict__ srcs,
                                             ushort* __restrict__ nrms) {
    __shared__ int hist[512];
    __shared__ int lcur[512];
    __shared__ int tot_s;
    int t = threadIdx.x;
    hist[t] = 0; hist[t + 256] = 0;
    __syncthreads();
    int b = blockIdx.x;
    int start = b * CAP;
    int end = cur[NBINS + b];
    for (int i = start + t; i < end; i += 256)
        atomicAdd(&hist[dbinned[i] & 511], 1);
    __syncthreads();
    int o0 = hist[t], o1 = hist[t + 256];
    int A0 = (o0 + 3) & ~3, A1 = (o1 + 3) & ~3;
    __syncthreads();
    hist[t] = A0; hist[t + 256] = A1;
    __syncthreads();
    for (int off = 1; off < 512; off <<= 1) {
        int v0 = (t >= off) ? hist[t - off] : 0;
        int v1 = (t + 256 >= off) ? hist[t + 256 - off] : 0;
        __syncthreads();
        hist[t] += v0; hist[t + 256] += v1;
        __syncthreads();
    }
    int e0 = hist[t] - A0, e1 = hist[t + 256] - A1;   // exclusive (aligned)
    if (t == 255) tot_s = hist[511];
    lcur[t] = start + e0;
    lcur[t + 256] = start + e1;
    int n0 = (b << 9) + t, n1 = n0 + 256;
    if (n0 < N_NODES) { cnt[n0] = o0; endp[n0] = start + e0 + o0; }
    if (n1 < N_NODES) { cnt[n1] = o1; endp[n1] = start + e1 + o1; }
    __syncthreads();
    for (int i = start + t; i < end; i += 256) {
        int p = dbinned[i];
        int s = p >> 9, dl = p & 511;
        int slot = atomicAdd(&lcur[dl], 1);
        srcs[slot] = s;
        nrms[slot] = f2bf(-dinv[s] * dinv[(b << 9) + dl]);
    }
    __syncthreads();
    // zero-fill per-node alignment pads
    for (int k = o0; k < A0; ++k) { srcs[start + e0 + k] = 0; nrms[start + e0 + k] = 0; }
    for (int k = o1; k < A1; ++k) { srcs[start + e1 + k] = 0; nrms[start + e1 + k] = 0; }
    // zero-fill 8-slot bin tail (layer's 8-chunk loop may overrun by <=7)
    if (t < 8) { srcs[start + tot_s + t] = 0; nrms[start + tot_s + t] = 0; }
}

// emb f32 -> bf16 (RNE), 8 elems/thread
__global__ __launch_bounds__(256) void embcvt(const float* __restrict__ in,
                                              ushort* __restrict__ out) {
    int i = (blockIdx.x * 256 + threadIdx.x) * 8;
    float4 v0 = *(const float4*)(in + i);
    float4 v1 = *(const float4*)(in + i + 4);
    uint4 o;
    o.x = (uint)f2bf(v0.x) | ((uint)f2bf(v0.y) << 16);
    o.y = (uint)f2bf(v0.z) | ((uint)f2bf(v0.w) << 16);
    o.z = (uint)f2bf(v1.x) | ((uint)f2bf(v1.y) << 16);
    o.w = (uint)f2bf(v1.z) | ((uint)f2bf(v1.w) << 16);
    *(uint4*)(out + i) = o;
}

// Fused layer: 16 nodes/wave; gather 4 edges per instruction (quarter-wave per
// edge, 4 features/lane), cross-quarter shfl_xor reduce, then MFMA GEMM.
// 256-thread blocks (WPB=4): 1563 blocks -> ~6 blocks/CU for latency hiding.
#define NPW 16
#define WPB 4
#define NPB (NPW * WPB)                       // 64
#define LB2 ((N_NODES + NPB - 1) / NPB)       // 1563

__global__ __launch_bounds__(256, 8) void cheb_layer(const ushort* __restrict__ x,
                                                     const int* __restrict__ srcs,
                                                     const ushort* __restrict__ nrms,
                                                     const int* __restrict__ endp,
                                                     const int* __restrict__ cnt,
                                                     const ushort* __restrict__ pk,
                                                     const float* __restrict__ bias,
                                                     ushort* __restrict__ out_bf,
                                                     float* __restrict__ out_f32,
                                                     int last) {
    __shared__ ushort sA[WPB][16][136];   // 17.4 KB

    int t = threadIdx.x;
    int lane = t & 63, wid = t >> 6;
    int c = lane & 15, q = lane >> 4;
    int qd = q, fg = c;
    int nb = blockIdx.x * NPB + wid * NPW;

    int nend = 0, ncnt = 0;
    if (lane < NPW && nb + lane < N_NODES) {
        nend = endp[nb + lane];
        ncnt = cnt[nb + lane];
    }

    const uint2* xr = (const uint2*)x;   // row = 16 uint2 (64 bf16)

    for (int g = 0; g < NPW; ++g) {
        int node = nb + g;
        int cn = __builtin_amdgcn_readlane(ncnt, g);
        int eend = __builtin_amdgcn_readlane(nend, g);
        int e = eend - cn;               // 4-aligned segment start
        float a0 = 0, a1 = 0, a2 = 0, a3 = 0;
        for (; e < eend; e += 8) {
            int4 sv = *(const int4*)(srcs + e);       // edges e..e+3 (uniform)
            int4 sw = *(const int4*)(srcs + e + 4);   // edges e+4..e+7
            uint2 nv = *(const uint2*)(nrms + e);     // 4 bf16 norms
            uint2 nw = *(const uint2*)(nrms + e + 4);
            int sA01 = (qd & 1) ? sv.y : sv.x;
            int sA23 = (qd & 1) ? sv.w : sv.z;
            int srcA = (qd & 2) ? sA23 : sA01;
            int sB01 = (qd & 1) ? sw.y : sw.x;
            int sB23 = (qd & 1) ? sw.w : sw.z;
            int srcB = (qd & 2) ? sB23 : sB01;
            uint nAp = (qd & 2) ? nv.y : nv.x;
            uint nBp = (qd & 2) ? nw.y : nw.x;
            float nAf = __uint_as_float((qd & 1) ? (nAp & 0xffff0000u) : (nAp << 16));
            float nBf = __uint_as_float((qd & 1) ? (nBp & 0xffff0000u) : (nBp << 16));
            nAf = (e + qd < eend) ? nAf : 0.0f;
            nBf = (e + 4 + qd < eend) ? nBf : 0.0f;
            uint2 gA = xr[(size_t)srcA * 16 + fg];
            uint2 gB = xr[(size_t)srcB * 16 + fg];
            a0 = fmaf(nAf, __uint_as_float(gA.x << 16), a0);
            a1 = fmaf(nAf, __uint_as_float(gA.x & 0xffff0000u), a1);
            a2 = fmaf(nAf, __uint_as_float(gA.y << 16), a2);
            a3 = fmaf(nAf, __uint_as_float(gA.y & 0xffff0000u), a3);
            a0 = fmaf(nBf, __uint_as_float(gB.x << 16), a0);
            a1 = fmaf(nBf, __uint_as_float(gB.x & 0xffff0000u), a1);
            a2 = fmaf(nBf, __uint_as_float(gB.y << 16), a2);
            a3 = fmaf(nBf, __uint_as_float(gB.y & 0xffff0000u), a3);
        }
        // sum the 4 quarter-wave partials (each holds same fg, different edges)
        a0 += __shfl_xor(a0, 16, 64); a1 += __shfl_xor(a1, 16, 64);
        a2 += __shfl_xor(a2, 16, 64); a3 += __shfl_xor(a3, 16, 64);
        a0 += __shfl_xor(a0, 32, 64); a1 += __shfl_xor(a1, 32, 64);
        a2 += __shfl_xor(a2, 32, 64); a3 += __shfl_xor(a3, 32, 64);
        int nidx = (node < N_NODES) ? node : 0;
        if (qd == 0) {
            uint2 xv = xr[(size_t)nidx * 16 + fg];
            *(uint2*)&sA[wid][g][4 * fg] = xv;
        }
        if (qd == 1) {
            uint2 p;
            p.x = (uint)f2bf(a0) | ((uint)f2bf(a1) << 16);
            p.y = (uint)f2bf(a2) | ((uint)f2bf(a3) << 16);
            *(uint2*)&sA[wid][g][64 + 4 * fg] = p;
        }
    }
    __builtin_amdgcn_wave_barrier();

    const short8* pk8 = (const short8*)pk;
    float4v C[4];
#pragma unroll
    for (int nt = 0; nt < 4; ++nt) {
        float b = bias[nt * 16 + c];
        C[nt] = (float4v){b, b, b, b};
    }
#pragma unroll
    for (int kt = 0; kt < 4; ++kt) {
        short8 af = *(const short8*)&sA[wid][c][kt * 32 + q * 8];
#pragma unroll
        for (int nt = 0; nt < 4; ++nt) {
            short8 bfr = pk8[(kt * 4 + nt) * 64 + lane];
            C[nt] = __builtin_amdgcn_mfma_f32_16x16x32_bf16(af, bfr, C[nt], 0, 0, 0);
        }
    }

#pragma unroll
    for (int nt = 0; nt < 4; ++nt) {
#pragma unroll
        for (int i = 0; i < 4; ++i) {
            int node = nb + q * 4 + i;
            if (node < N_NODES) {
                float v = C[nt][i];
                if (!last) {
                    v = fmaxf(v, 0.0f);
                    out_bf[(size_t)node * NF + nt * 16 + c] = f2bf(v);
                } else {
                    out_f32[(size_t)node * NF + nt * 16 + c] = v;
                }
            }
        }
    }
}

extern "C" void kernel_launch(void* const* d_in, const int* in_sizes, int n_in,
                              void* d_out, int out_size, void* d_ws, size_t ws_size,
                              hipStream_t stream) {
    const int* ei = (const int*)d_in[0];
    const int* row = ei;
    const int* col = ei + N_EDGES;
    const float* emb = (const float*)d_in[1];
    const float* W1_0 = (const float*)d_in[2];
    const float* W1_1 = (const float*)d_in[3];
    const float* b1 = (const float*)d_in[4];
    const float* W2_0 = (const float*)d_in[5];
    const float* W2_1 = (const float*)d_in[6];
    const float* b2 = (const float*)d_in[7];
    float* out = (float*)d_out;

    char* ws = (char*)d_ws;
    int* cnt = (int*)(ws + OFF_CNT);
    int* endp = (int*)(ws + OFF_ENDP);
    float* dinv = (float*)(ws + OFF_DINV);
    int* cur = (int*)(ws + OFF_CUR);
    ushort* pk = (ushort*)(ws + OFF_PKW);
    int* srcs = (int*)(ws + OFF_SRCS);
    ushort* nrms = (ushort*)(ws + OFF_NRMS);
    ushort* sbinned = (ushort*)(ws + OFF_SBIN);
    int* dbinned = (int*)(ws + OFF_DBIN);
    ushort* emb_bf = (ushort*)(ws + OFF_EMBBF);   // after binD2
    ushort* h_bf = (ushort*)(ws + OFF_HBF);

    packW<<<9, 256, 0, stream>>>(W1_0, W1_1, W2_0, W2_1, pk, cur);
    binsort<<<NBLK, 256, 0, stream>>>(row, col, cur, sbinned, dbinned);
    binD1<<<NBINS, 256, 0, stream>>>(sbinned, cur, dinv);
    binD2<<<NBINS, 256, 0, stream>>>(dbinned, cur, dinv, cnt, endp, srcs, nrms);
    embcvt<<<(N_NODES * NF) / 2048, 256, 0, stream>>>(emb, emb_bf);

    cheb_layer<<<LB2, 256, 0, stream>>>(emb_bf, srcs, nrms, endp, cnt, pk, b1, h_bf, nullptr, 0);
    cheb_layer<<<LB2, 256, 0, stream>>>(h_bf, srcs, nrms, endp, cnt, pk + 8192, b2, nullptr, out, 1);
}

// Round 12
// 227.674 us; speedup vs baseline: 1.4511x; 1.0154x over previous
//
#include <hip/hip_runtime.h>

#define N_NODES 100000
#define N_EDGES 1200000
#define NF 64

typedef __attribute__((ext_vector_type(8))) short short8;
typedef __attribute__((ext_vector_type(4))) float float4v;

__device__ __forceinline__ ushort f2bf(float f) {
    unsigned u = __float_as_uint(f);
    return (ushort)((u + 0x7FFF + ((u >> 16) & 1)) >> 16);  // RNE
}

// binning: bin = node >> 9, 196 bins of 512 nodes, fixed capacity per bin
#define NBINS 196
#define CAP 7680                 // mean 6144, sigma ~78; aligned total <= ~7400
#define EPB 2560
#define NBLK 469                 // ceil(1200000/2560)

// ---------------- workspace layout (bytes), peak ~35.9 MB ----------------
// CRITICAL ORDERING: EMBBF overlays SBIN/DBIN staging -> embcvt MUST launch
// after binD2 (r11 regression: merged into prep -> clobbered by binsort).
#define OFF_CNT    0             // int[100000]
#define OFF_ENDP   400128        // int[100000]
#define OFF_DINV   800256        // float[100000] (dead after binD2)
#define OFF_CUR    1200384       // int[392] global bin cursors
#define OFF_PKW    1202048       // ushort[2*1024*8] = 32 KB packed B-fragments
#define OFF_SRCS   1234816       // int[196*7680]   = 6.02 MB (final, dst-binned)
#define OFF_NRMS   7255936       // ushort[196*7680] = 3.01 MB
#define OFF_SBIN   10266496      // ushort[196*7680] 3.01 MB (staging, dead after binD1)
#define OFF_DBIN   16287616      // int[196*7680]    6.02 MB (staging, dead after binD2)
#define OFF_EMBBF  10266496      // ushort[6.4M] 12.8 MB (overlays SBIN/DBIN, after binD2)
#define OFF_HBF    23066496      // ushort[6.4M] 12.8 MB -> ends 35,866,496

// blocks 0-7: pack W into B-fragment order; block 8: init cursors
__global__ __launch_bounds__(256) void prep(const float* __restrict__ W10,
                                            const float* __restrict__ W11,
                                            const float* __restrict__ W20,
                                            const float* __restrict__ W21,
                                            ushort* __restrict__ pk,
                                            int* __restrict__ cur) {
    int b = blockIdx.x;
    int t = threadIdx.x;
    if (b == 8) {
        for (int i = t; i < 2 * NBINS; i += 256)
            cur[i] = (i < NBINS ? i : i - NBINS) * CAP;
        return;
    }
    int idx = b * 256 + t;   // [0, 2048)
    int layer = idx >> 10;
    int rest = idx & 1023;
    int f = rest >> 6, L = rest & 63;
    int n = (f & 3) * 16 + (L & 15);
    int kb = (f >> 2) * 32 + ((L >> 4) << 3);
#pragma unroll
    for (int j = 0; j < 8; ++j) {
        int k = kb + j;
        const float* W = layer ? ((k < 64) ? W20 : W21) : ((k < 64) ? W10 : W11);
        pk[idx * 8 + j] = f2bf(W[(k & 63) * 64 + n]);
    }
}

// single-pass binned counting sort: LDS hist -> chunk reservation -> scatter.
// Edges cached in LDS so the scatter pass doesn't re-read global.
__global__ __launch_bounds__(256) void binsort(const int* __restrict__ row,
                                               const int* __restrict__ col,
                                               int* __restrict__ cur,
                                               ushort* __restrict__ sbinned,
                                               int* __restrict__ dbinned) {
    __shared__ int2 ecache[EPB];               // 20 KB
    __shared__ int sh[NBINS], dh[NBINS];
    __shared__ int sbase[NBINS], dbase[NBINS];
    int t = threadIdx.x;
    if (t < NBINS) { sh[t] = 0; dh[t] = 0; }
    __syncthreads();
    int base = blockIdx.x * EPB;
    for (int k = 0; k < EPB / 256; ++k) {
        int e = base + k * 256 + t;
        int s = -1, d = -1;
        if (e < N_EDGES) { s = row[e]; d = col[e]; }
        ecache[k * 256 + t] = make_int2(s, d);
        if (s >= 0 && s != d) {
            atomicAdd(&sh[s >> 9], 1);
            atomicAdd(&dh[d >> 9], 1);
        }
    }
    __syncthreads();
    if (t < NBINS) {
        sbase[t] = atomicAdd(&cur[t], sh[t]);
        dbase[t] = atomicAdd(&cur[NBINS + t], dh[t]);
    }
    __syncthreads();
    for (int k = 0; k < EPB / 256; ++k) {
        int2 p = ecache[k * 256 + t];
        int s = p.x, d = p.y;
        if (s >= 0 && s != d) {
            int ss = atomicAdd(&sbase[s >> 9], 1);
            sbinned[ss] = (ushort)(s & 511);
            int ds = atomicAdd(&dbase[d >> 9], 1);
            dbinned[ds] = (s << 9) | (d & 511);
        }
    }
}

// per src-bin per-node histogram -> dinv (512 threads, 1 node/thread)
__global__ __launch_bounds__(512) void binD1(const ushort* __restrict__ sbinned,
                                             const int* __restrict__ cur,
                                             float* __restrict__ dinv) {
    __shared__ int hist[512];
    int t = threadIdx.x;
    hist[t] = 0;
    __syncthreads();
    int b = blockIdx.x;
    int start = b * CAP;
    int end = cur[b];
    for (int i = start + t; i < end; i += 512)
        atomicAdd(&hist[sbinned[i]], 1);
    __syncthreads();
    int n0 = (b << 9) + t;
    if (n0 < N_NODES) dinv[n0] = hist[t] ? rsqrtf((float)hist[t]) : 0.0f;
}

// per dst-bin: hist + scan of 4-aligned counts -> cnt/endp + srcs/nrms scatter
__global__ __launch_bounds__(512) void binD2(const int* __restrict__ dbinned,
                                             const int* __restrict__ cur,
                                             const float* __restrict__ dinv,
                                             int* __restrict__ cnt,
                                             int* __restrict__ endp,
                                             int* __restrict__ srcs,
                                             ushort* __restrict__ nrms) {
    __shared__ int hist[512];
    __shared__ int lcur[512];
    __shared__ int tot_s;
    int t = threadIdx.x;
    hist[t] = 0;
    __syncthreads();
    int b = blockIdx.x;
    int start = b * CAP;
    int end = cur[NBINS + b];
    for (int i = start + t; i < end; i += 512)
        atomicAdd(&hist[dbinned[i] & 511], 1);
    __syncthreads();
    int o0 = hist[t];
    int A0 = (o0 + 3) & ~3;
    __syncthreads();
    hist[t] = A0;
    __syncthreads();
    for (int off = 1; off < 512; off <<= 1) {
        int v = (t >= off) ? hist[t - off] : 0;
        __syncthreads();
        hist[t] += v;
        __syncthreads();
    }
    int e0 = hist[t] - A0;   // exclusive (aligned)
    if (t == 511) tot_s = hist[511];
    lcur[t] = start + e0;
    int n0 = (b << 9) + t;
    if (n0 < N_NODES) { cnt[n0] = o0; endp[n0] = start + e0 + o0; }
    __syncthreads();
    for (int i = start + t; i < end; i += 512) {
        int p = dbinned[i];
        int s = p >> 9, dl = p & 511;
        int slot = atomicAdd(&lcur[dl], 1);
        srcs[slot] = s;
        nrms[slot] = f2bf(-dinv[s] * dinv[(b << 9) + dl]);
    }
    __syncthreads();
    // zero-fill per-node alignment pads
    for (int k = o0; k < A0; ++k) { srcs[start + e0 + k] = 0; nrms[start + e0 + k] = 0; }
    // zero-fill 8-slot bin tail (layer's 8-chunk loop may overrun by <=7)
    if (t < 8) { srcs[start + tot_s + t] = 0; nrms[start + tot_s + t] = 0; }
}

// emb f32 -> bf16 (RNE), 8 elems/thread — MUST run after binD2 (overlay)
__global__ __launch_bounds__(256) void embcvt(const float* __restrict__ in,
                                              ushort* __restrict__ out) {
    int i = (blockIdx.x * 256 + threadIdx.x) * 8;
    float4 v0 = *(const float4*)(in + i);
    float4 v1 = *(const float4*)(in + i + 4);
    uint4 o;
    o.x = (uint)f2bf(v0.x) | ((uint)f2bf(v0.y) << 16);
    o.y = (uint)f2bf(v0.z) | ((uint)f2bf(v0.w) << 16);
    o.z = (uint)f2bf(v1.x) | ((uint)f2bf(v1.y) << 16);
    o.w = (uint)f2bf(v1.z) | ((uint)f2bf(v1.w) << 16);
    *(uint4*)(out + i) = o;
}

// Fused layer: 16 nodes/wave; gather 4 edges per instruction (quarter-wave per
// edge, 4 features/lane), cross-quarter shfl_xor reduce, then MFMA GEMM.
// 128-thread blocks (WPB=2): 3125 blocks -> ~12 blocks/CU.
#define NPW 16
#define WPB 2
#define NPB (NPW * WPB)                       // 32
#define LB2 ((N_NODES + NPB - 1) / NPB)       // 3125

__global__ __launch_bounds__(128, 8) void cheb_layer(const ushort* __restrict__ x,
                                                     const int* __restrict__ srcs,
                                                     const ushort* __restrict__ nrms,
                                                     const int* __restrict__ endp,
                                                     const int* __restrict__ cnt,
                                                     const ushort* __restrict__ pk,
                                                     const float* __restrict__ bias,
                                                     ushort* __restrict__ out_bf,
                                                     float* __restrict__ out_f32,
                                                     int last) {
    __shared__ ushort sA[WPB][16][136];   // 8.7 KB

    int t = threadIdx.x;
    int lane = t & 63, wid = t >> 6;
    int c = lane & 15, q = lane >> 4;
    int qd = q, fg = c;
    int nb = blockIdx.x * NPB + wid * NPW;

    int nend = 0, ncnt = 0;
    if (lane < NPW && nb + lane < N_NODES) {
        nend = endp[nb + lane];
        ncnt = cnt[nb + lane];
    }

    const uint2* xr = (const uint2*)x;   // row = 16 uint2 (64 bf16)

    for (int g = 0; g < NPW; ++g) {
        int node = nb + g;
        int cn = __builtin_amdgcn_readlane(ncnt, g);
        int eend = __builtin_amdgcn_readlane(nend, g);
        int e = eend - cn;               // 4-aligned segment start
        float a0 = 0, a1 = 0, a2 = 0, a3 = 0;
        for (; e < eend; e += 8) {
            int4 sv = *(const int4*)(srcs + e);       // edges e..e+3 (uniform)
            int4 sw = *(const int4*)(srcs + e + 4);   // edges e+4..e+7
            uint2 nv = *(const uint2*)(nrms + e);     // 4 bf16 norms
            uint2 nw = *(const uint2*)(nrms + e + 4);
            int sA01 = (qd & 1) ? sv.y : sv.x;
            int sA23 = (qd & 1) ? sv.w : sv.z;
            int srcA = (qd & 2) ? sA23 : sA01;
            int sB01 = (qd & 1) ? sw.y : sw.x;
            int sB23 = (qd & 1) ? sw.w : sw.z;
            int srcB = (qd & 2) ? sB23 : sB01;
            uint nAp = (qd & 2) ? nv.y : nv.x;
            uint nBp = (qd & 2) ? nw.y : nw.x;
            float nAf = __uint_as_float((qd & 1) ? (nAp & 0xffff0000u) : (nAp << 16));
            float nBf = __uint_as_float((qd & 1) ? (nBp & 0xffff0000u) : (nBp << 16));
            nAf = (e + qd < eend) ? nAf : 0.0f;
            nBf = (e + 4 + qd < eend) ? nBf : 0.0f;
            uint2 gA = xr[(size_t)srcA * 16 + fg];
            uint2 gB = xr[(size_t)srcB * 16 + fg];
            a0 = fmaf(nAf, __uint_as_float(gA.x << 16), a0);
            a1 = fmaf(nAf, __uint_as_float(gA.x & 0xffff0000u), a1);
            a2 = fmaf(nAf, __uint_as_float(gA.y << 16), a2);
            a3 = fmaf(nAf, __uint_as_float(gA.y & 0xffff0000u), a3);
            a0 = fmaf(nBf, __uint_as_float(gB.x << 16), a0);
            a1 = fmaf(nBf, __uint_as_float(gB.x & 0xffff0000u), a1);
            a2 = fmaf(nBf, __uint_as_float(gB.y << 16), a2);
            a3 = fmaf(nBf, __uint_as_float(gB.y & 0xffff0000u), a3);
        }
        // sum the 4 quarter-wave partials (each holds same fg, different edges)
        a0 += __shfl_xor(a0, 16, 64); a1 += __shfl_xor(a1, 16, 64);
        a2 += __shfl_xor(a2, 16, 64); a3 += __shfl_xor(a3, 16, 64);
        a0 += __shfl_xor(a0, 32, 64); a1 += __shfl_xor(a1, 32, 64);
        a2 += __shfl_xor(a2, 32, 64); a3 += __shfl_xor(a3, 32, 64);
        int nidx = (node < N_NODES) ? node : 0;
        if (qd == 0) {
            uint2 xv = xr[(size_t)nidx * 16 + fg];
            *(uint2*)&sA[wid][g][4 * fg] = xv;
        }
        if (qd == 1) {
            uint2 p;
            p.x = (uint)f2bf(a0) | ((uint)f2bf(a1) << 16);
            p.y = (uint)f2bf(a2) | ((uint)f2bf(a3) << 16);
            *(uint2*)&sA[wid][g][64 + 4 * fg] = p;
        }
    }
    __builtin_amdgcn_wave_barrier();

    const short8* pk8 = (const short8*)pk;
    float4v C[4];
#pragma unroll
    for (int nt = 0; nt < 4; ++nt) {
        float b = bias[nt * 16 + c];
        C[nt] = (float4v){b, b, b, b};
    }
#pragma unroll
    for (int kt = 0; kt < 4; ++kt) {
        short8 af = *(const short8*)&sA[wid][c][kt * 32 + q * 8];
#pragma unroll
        for (int nt = 0; nt < 4; ++nt) {
            short8 bfr = pk8[(kt * 4 + nt) * 64 + lane];
            C[nt] = __builtin_amdgcn_mfma_f32_16x16x32_bf16(af, bfr, C[nt], 0, 0, 0);
        }
    }

#pragma unroll
    for (int nt = 0; nt < 4; ++nt) {
#pragma unroll
        for (int i = 0; i < 4; ++i) {
            int node = nb + q * 4 + i;
            if (node < N_NODES) {
                float v = C[nt][i];
                if (!last) {
                    v = fmaxf(v, 0.0f);
                    out_bf[(size_t)node * NF + nt * 16 + c] = f2bf(v);
                } else {
                    out_f32[(size_t)node * NF + nt * 16 + c] = v;
                }
            }
        }
    }
}

extern "C" void kernel_launch(void* const* d_in, const int* in_sizes, int n_in,
                              void* d_out, int out_size, void* d_ws, size_t ws_size,
                              hipStream_t stream) {
    const int* ei = (const int*)d_in[0];
    const int* row = ei;
    const int* col = ei + N_EDGES;
    const float* emb = (const float*)d_in[1];
    const float* W1_0 = (const float*)d_in[2];
    const float* W1_1 = (const float*)d_in[3];
    const float* b1 = (const float*)d_in[4];
    const float* W2_0 = (const float*)d_in[5];
    const float* W2_1 = (const float*)d_in[6];
    const float* b2 = (const float*)d_in[7];
    float* out = (float*)d_out;

    char* ws = (char*)d_ws;
    int* cnt = (int*)(ws + OFF_CNT);
    int* endp = (int*)(ws + OFF_ENDP);
    float* dinv = (float*)(ws + OFF_DINV);
    int* cur = (int*)(ws + OFF_CUR);
    ushort* pk = (ushort*)(ws + OFF_PKW);
    int* srcs = (int*)(ws + OFF_SRCS);
    ushort* nrms = (ushort*)(ws + OFF_NRMS);
    ushort* sbinned = (ushort*)(ws + OFF_SBIN);
    int* dbinned = (int*)(ws + OFF_DBIN);
    ushort* emb_bf = (ushort*)(ws + OFF_EMBBF);   // valid only after binD2
    ushort* h_bf = (ushort*)(ws + OFF_HBF);

    prep<<<9, 256, 0, stream>>>(W1_0, W1_1, W2_0, W2_1, pk, cur);
    binsort<<<NBLK, 256, 0, stream>>>(row, col, cur, sbinned, dbinned);
    binD1<<<NBINS, 512, 0, stream>>>(sbinned, cur, dinv);
    binD2<<<NBINS, 512, 0, stream>>>(dbinned, cur, dinv, cnt, endp, srcs, nrms);
    embcvt<<<(N_NODES * NF) / 2048, 256, 0, stream>>>(emb, emb_bf);  // after binD2!

    cheb_layer<<<LB2, 128, 0, stream>>>(emb_bf, srcs, nrms, endp, cnt, pk, b1, h_bf, nullptr, 0);
    cheb_layer<<<LB2, 128, 0, stream>>>(h_bf, srcs, nrms, endp, cnt, pk + 8192, b2, nullptr, out, 1);
}

// Round 13
// 220.910 us; speedup vs baseline: 1.4955x; 1.0306x over previous
//
#include <hip/hip_runtime.h>

#define N_NODES 100000
#define N_EDGES 1200000
#define NF 64

typedef __attribute__((ext_vector_type(8))) short short8;
typedef __attribute__((ext_vector_type(4))) float float4v;

__device__ __forceinline__ ushort f2bf(float f) {
    unsigned u = __float_as_uint(f);
    return (ushort)((u + 0x7FFF + ((u >> 16) & 1)) >> 16);  // RNE
}

// binning: bin = node >> 9, 196 bins of 512 nodes, fixed capacity per bin
#define NBINS 196
#define CAP 7680                 // max used ~6420 + pads ~800 + 16 tail < 7680
#define EPB 2560
#define NBLK 469                 // ceil(1200000/2560)

// ---------------- workspace layout (bytes), flat, no overlays (~45 MB of 268 MB)
#define OFF_CNT    0             // int[100000]
#define OFF_ENDP   400128        // int[100000]
#define OFF_DINV   800256        // float[100000]
#define OFF_CUR    1200384       // int[392] global bin cursors
#define OFF_PKW    1202048       // ushort[2*1024*8] = 32 KB packed B-fragments
#define OFF_SRCS   1234816       // int[196*7680]    = 6.02 MB (final, dst-binned)
#define OFF_NRMS   7255936       // ushort[196*7680] = 3.01 MB
#define OFF_SBIN   10266496      // ushort[196*7680] = 3.01 MB staging
#define OFF_DBIN   13277056      // int[196*7680]    = 6.02 MB staging
#define OFF_EMBBF  19298176      // ushort[6.4M] = 12.8 MB
#define OFF_HBF    32098176      // ushort[6.4M] = 12.8 MB -> ends 44,898,176

// blocks 0-7: pack W into B-fragment order; block 8: init cursors;
// blocks 9+: emb f32 -> bf16 (no overlay hazard now)
__global__ __launch_bounds__(256) void prep(const float* __restrict__ W10,
                                            const float* __restrict__ W11,
                                            const float* __restrict__ W20,
                                            const float* __restrict__ W21,
                                            ushort* __restrict__ pk,
                                            int* __restrict__ cur,
                                            const float* __restrict__ emb,
                                            ushort* __restrict__ emb_bf) {
    int b = blockIdx.x;
    int t = threadIdx.x;
    if (b < 8) {
        int idx = b * 256 + t;   // [0, 2048)
        int layer = idx >> 10;
        int rest = idx & 1023;
        int f = rest >> 6, L = rest & 63;
        int n = (f & 3) * 16 + (L & 15);
        int kb = (f >> 2) * 32 + ((L >> 4) << 3);
#pragma unroll
        for (int j = 0; j < 8; ++j) {
            int k = kb + j;
            const float* W = layer ? ((k < 64) ? W20 : W21) : ((k < 64) ? W10 : W11);
            pk[idx * 8 + j] = f2bf(W[(k & 63) * 64 + n]);
        }
    } else if (b == 8) {
        for (int i = t; i < 2 * NBINS; i += 256)
            cur[i] = (i < NBINS ? i : i - NBINS) * CAP;
    } else {
        int i = ((b - 9) * 256 + t) * 8;
        float4 v0 = *(const float4*)(emb + i);
        float4 v1 = *(const float4*)(emb + i + 4);
        uint4 o;
        o.x = (uint)f2bf(v0.x) | ((uint)f2bf(v0.y) << 16);
        o.y = (uint)f2bf(v0.z) | ((uint)f2bf(v0.w) << 16);
        o.z = (uint)f2bf(v1.x) | ((uint)f2bf(v1.y) << 16);
        o.w = (uint)f2bf(v1.z) | ((uint)f2bf(v1.w) << 16);
        *(uint4*)(emb_bf + i) = o;
    }
}

// single-pass binned counting sort: LDS hist -> chunk reservation -> scatter.
__global__ __launch_bounds__(256) void binsort(const int* __restrict__ row,
                                               const int* __restrict__ col,
                                               int* __restrict__ cur,
                                               ushort* __restrict__ sbinned,
                                               int* __restrict__ dbinned) {
    __shared__ int2 ecache[EPB];               // 20 KB
    __shared__ int sh[NBINS], dh[NBINS];
    __shared__ int sbase[NBINS], dbase[NBINS];
    int t = threadIdx.x;
    if (t < NBINS) { sh[t] = 0; dh[t] = 0; }
    __syncthreads();
    int base = blockIdx.x * EPB;
    for (int k = 0; k < EPB / 256; ++k) {
        int e = base + k * 256 + t;
        int s = -1, d = -1;
        if (e < N_EDGES) { s = row[e]; d = col[e]; }
        ecache[k * 256 + t] = make_int2(s, d);
        if (s >= 0 && s != d) {
            atomicAdd(&sh[s >> 9], 1);
            atomicAdd(&dh[d >> 9], 1);
        }
    }
    __syncthreads();
    if (t < NBINS) {
        sbase[t] = atomicAdd(&cur[t], sh[t]);
        dbase[t] = atomicAdd(&cur[NBINS + t], dh[t]);
    }
    __syncthreads();
    for (int k = 0; k < EPB / 256; ++k) {
        int2 p = ecache[k * 256 + t];
        int s = p.x, d = p.y;
        if (s >= 0 && s != d) {
            int ss = atomicAdd(&sbase[s >> 9], 1);
            sbinned[ss] = (ushort)(s & 511);
            int ds = atomicAdd(&dbase[d >> 9], 1);
            dbinned[ds] = (s << 9) | (d & 511);
        }
    }
}

// per src-bin per-node histogram -> dinv (512 threads, 1 node/thread)
__global__ __launch_bounds__(512) void binD1(const ushort* __restrict__ sbinned,
                                             const int* __restrict__ cur,
                                             float* __restrict__ dinv) {
    __shared__ int hist[512];
    int t = threadIdx.x;
    hist[t] = 0;
    __syncthreads();
    int b = blockIdx.x;
    int start = b * CAP;
    int end = cur[b];
    for (int i = start + t; i < end; i += 512)
        atomicAdd(&hist[sbinned[i]], 1);
    __syncthreads();
    int n0 = (b << 9) + t;
    if (n0 < N_NODES) dinv[n0] = hist[t] ? rsqrtf((float)hist[t]) : 0.0f;
}

// per dst-bin: hist + scan of 4-aligned counts -> cnt/endp + srcs/nrms scatter
__global__ __launch_bounds__(512) void binD2(const int* __restrict__ dbinned,
                                             const int* __restrict__ cur,
                                             const float* __restrict__ dinv,
                                             int* __restrict__ cnt,
                                             int* __restrict__ endp,
                                             int* __restrict__ srcs,
                                             ushort* __restrict__ nrms) {
    __shared__ int hist[512];
    __shared__ int lcur[512];
    __shared__ int tot_s;
    int t = threadIdx.x;
    hist[t] = 0;
    __syncthreads();
    int b = blockIdx.x;
    int start = b * CAP;
    int end = cur[NBINS + b];
    for (int i = start + t; i < end; i += 512)
        atomicAdd(&hist[dbinned[i] & 511], 1);
    __syncthreads();
    int o0 = hist[t];
    int A0 = (o0 + 3) & ~3;
    __syncthreads();
    hist[t] = A0;
    __syncthreads();
    for (int off = 1; off < 512; off <<= 1) {
        int v = (t >= off) ? hist[t - off] : 0;
        __syncthreads();
        hist[t] += v;
        __syncthreads();
    }
    int e0 = hist[t] - A0;   // exclusive (aligned)
    if (t == 511) tot_s = hist[511];
    lcur[t] = start + e0;
    int n0 = (b << 9) + t;
    if (n0 < N_NODES) { cnt[n0] = o0; endp[n0] = start + e0 + o0; }
    __syncthreads();
    for (int i = start + t; i < end; i += 512) {
        int p = dbinned[i];
        int s = p >> 9, dl = p & 511;
        int slot = atomicAdd(&lcur[dl], 1);
        srcs[slot] = s;
        nrms[slot] = f2bf(-dinv[s] * dinv[(b << 9) + dl]);
    }
    __syncthreads();
    // zero-fill per-node alignment pads
    for (int k = o0; k < A0; ++k) { srcs[start + e0 + k] = 0; nrms[start + e0 + k] = 0; }
    // zero-fill 16-slot bin tail (layer's straight-line 2x8 chunks may overread)
    if (t < 16) { srcs[start + tot_s + t] = 0; nrms[start + tot_s + t] = 0; }
}

// Fused layer: 16 nodes/wave; gather 4 edges per instruction (quarter-wave per
// edge, 4 features/lane). Straight-line 2x8-edge chunks (12 vmem in flight,
// branch-free for cn<=16 ~ 90% of nodes) + masked loop for heavy nodes.
#define NPW 16
#define WPB 2
#define NPB (NPW * WPB)                       // 32
#define LB2 ((N_NODES + NPB - 1) / NPB)       // 3125

__global__ __launch_bounds__(128, 8) void cheb_layer(const ushort* __restrict__ x,
                                                     const int* __restrict__ srcs,
                                                     const ushort* __restrict__ nrms,
                                                     const int* __restrict__ endp,
                                                     const int* __restrict__ cnt,
                                                     const ushort* __restrict__ pk,
                                                     const float* __restrict__ bias,
                                                     ushort* __restrict__ out_bf,
                                                     float* __restrict__ out_f32,
                                                     int last) {
    __shared__ ushort sA[WPB][16][136];   // 8.7 KB

    int t = threadIdx.x;
    int lane = t & 63, wid = t >> 6;
    int c = lane & 15, q = lane >> 4;
    int qd = q, fg = c;
    int nb = blockIdx.x * NPB + wid * NPW;

    int nend = 0, ncnt = 0;
    if (lane < NPW && nb + lane < N_NODES) {
        nend = endp[nb + lane];
        ncnt = cnt[nb + lane];
    }

    const uint2* xr = (const uint2*)x;   // row = 16 uint2 (64 bf16)

    for (int g = 0; g < NPW; ++g) {
        int node = nb + g;
        int cn = __builtin_amdgcn_readlane(ncnt, g);
        int eend = __builtin_amdgcn_readlane(nend, g);
        int e = eend - cn;               // 4-aligned segment start
        float a0 = 0, a1 = 0, a2 = 0, a3 = 0;

        auto chunk8 = [&](int eb) {
            int4 sv = *(const int4*)(srcs + eb);       // edges eb..eb+3
            int4 sw = *(const int4*)(srcs + eb + 4);   // edges eb+4..eb+7
            uint2 nv = *(const uint2*)(nrms + eb);
            uint2 nw = *(const uint2*)(nrms + eb + 4);
            int sA01 = (qd & 1) ? sv.y : sv.x;
            int sA23 = (qd & 1) ? sv.w : sv.z;
            int srcA = (qd & 2) ? sA23 : sA01;
            int sB01 = (qd & 1) ? sw.y : sw.x;
            int sB23 = (qd & 1) ? sw.w : sw.z;
            int srcB = (qd & 2) ? sB23 : sB01;
            uint nAp = (qd & 2) ? nv.y : nv.x;
            uint nBp = (qd & 2) ? nw.y : nw.x;
            float nAf = __uint_as_float((qd & 1) ? (nAp & 0xffff0000u) : (nAp << 16));
            float nBf = __uint_as_float((qd & 1) ? (nBp & 0xffff0000u) : (nBp << 16));
            nAf = (eb + qd < eend) ? nAf : 0.0f;
            nBf = (eb + 4 + qd < eend) ? nBf : 0.0f;
            uint2 gA = xr[(size_t)srcA * 16 + fg];
            uint2 gB = xr[(size_t)srcB * 16 + fg];
            a0 = fmaf(nAf, __uint_as_float(gA.x << 16), a0);
            a1 = fmaf(nAf, __uint_as_float(gA.x & 0xffff0000u), a1);
            a2 = fmaf(nAf, __uint_as_float(gA.y << 16), a2);
            a3 = fmaf(nAf, __uint_as_float(gA.y & 0xffff0000u), a3);
            a0 = fmaf(nBf, __uint_as_float(gB.x << 16), a0);
            a1 = fmaf(nBf, __uint_as_float(gB.x & 0xffff0000u), a1);
            a2 = fmaf(nBf, __uint_as_float(gB.y << 16), a2);
            a3 = fmaf(nBf, __uint_as_float(gB.y & 0xffff0000u), a3);
        };

        chunk8(e);          // masked; reads always safe (16-slot bin tail)
        chunk8(e + 8);
        e += 16;
        for (; e < eend; e += 8) chunk8(e);   // rare heavy nodes (cn > 16)

        // sum the 4 quarter-wave partials
        a0 += __shfl_xor(a0, 16, 64); a1 += __shfl_xor(a1, 16, 64);
        a2 += __shfl_xor(a2, 16, 64); a3 += __shfl_xor(a3, 16, 64);
        a0 += __shfl_xor(a0, 32, 64); a1 += __shfl_xor(a1, 32, 64);
        a2 += __shfl_xor(a2, 32, 64); a3 += __shfl_xor(a3, 32, 64);
        int nidx = (node < N_NODES) ? node : 0;
        if (qd == 0) {
            uint2 xv = xr[(size_t)nidx * 16 + fg];
            *(uint2*)&sA[wid][g][4 * fg] = xv;
        }
        if (qd == 1) {
            uint2 p;
            p.x = (uint)f2bf(a0) | ((uint)f2bf(a1) << 16);
            p.y = (uint)f2bf(a2) | ((uint)f2bf(a3) << 16);
            *(uint2*)&sA[wid][g][64 + 4 * fg] = p;
        }
    }
    __builtin_amdgcn_wave_barrier();

    const short8* pk8 = (const short8*)pk;
    float4v C[4];
#pragma unroll
    for (int nt = 0; nt < 4; ++nt) {
        float b = bias[nt * 16 + c];
        C[nt] = (float4v){b, b, b, b};
    }
#pragma unroll
    for (int kt = 0; kt < 4; ++kt) {
        short8 af = *(const short8*)&sA[wid][c][kt * 32 + q * 8];
#pragma unroll
        for (int nt = 0; nt < 4; ++nt) {
            short8 bfr = pk8[(kt * 4 + nt) * 64 + lane];
            C[nt] = __builtin_amdgcn_mfma_f32_16x16x32_bf16(af, bfr, C[nt], 0, 0, 0);
        }
    }

#pragma unroll
    for (int nt = 0; nt < 4; ++nt) {
#pragma unroll
        for (int i = 0; i < 4; ++i) {
            int node = nb + q * 4 + i;
            if (node < N_NODES) {
                float v = C[nt][i];
                if (!last) {
                    v = fmaxf(v, 0.0f);
                    out_bf[(size_t)node * NF + nt * 16 + c] = f2bf(v);
                } else {
                    out_f32[(size_t)node * NF + nt * 16 + c] = v;
                }
            }
        }
    }
}

extern "C" void kernel_launch(void* const* d_in, const int* in_sizes, int n_in,
                              void* d_out, int out_size, void* d_ws, size_t ws_size,
                              hipStream_t stream) {
    const int* ei = (const int*)d_in[0];
    const int* row = ei;
    const int* col = ei + N_EDGES;
    const float* emb = (const float*)d_in[1];
    const float* W1_0 = (const float*)d_in[2];
    const float* W1_1 = (const float*)d_in[3];
    const float* b1 = (const float*)d_in[4];
    const float* W2_0 = (const float*)d_in[5];
    const float* W2_1 = (const float*)d_in[6];
    const float* b2 = (const float*)d_in[7];
    float* out = (float*)d_out;

    char* ws = (char*)d_ws;
    int* cnt = (int*)(ws + OFF_CNT);
    int* endp = (int*)(ws + OFF_ENDP);
    float* dinv = (float*)(ws + OFF_DINV);
    int* cur = (int*)(ws + OFF_CUR);
    ushort* pk = (ushort*)(ws + OFF_PKW);
    int* srcs = (int*)(ws + OFF_SRCS);
    ushort* nrms = (ushort*)(ws + OFF_NRMS);
    ushort* sbinned = (ushort*)(ws + OFF_SBIN);
    int* dbinned = (int*)(ws + OFF_DBIN);
    ushort* emb_bf = (ushort*)(ws + OFF_EMBBF);
    ushort* h_bf = (ushort*)(ws + OFF_HBF);

    prep<<<9 + 3125, 256, 0, stream>>>(W1_0, W1_1, W2_0, W2_1, pk, cur, emb, emb_bf);
    binsort<<<NBLK, 256, 0, stream>>>(row, col, cur, sbinned, dbinned);
    binD1<<<NBINS, 512, 0, stream>>>(sbinned, cur, dinv);
    binD2<<<NBINS, 512, 0, stream>>>(dbinned, cur, dinv, cnt, endp, srcs, nrms);

    cheb_layer<<<LB2, 128, 0, stream>>>(emb_bf, srcs, nrms, endp, cnt, pk, b1, h_bf, nullptr, 0);
    cheb_layer<<<LB2, 128, 0, stream>>>(h_bf, srcs, nrms, endp, cnt, pk + 8192, b2, nullptr, out, 1);
}

// Round 14
// 219.234 us; speedup vs baseline: 1.5069x; 1.0076x over previous
//
#include <hip/hip_runtime.h>

#define N_NODES 100000
#define N_EDGES 1200000
#define NF 64

typedef __attribute__((ext_vector_type(8))) short short8;
typedef __attribute__((ext_vector_type(4))) float float4v;

__device__ __forceinline__ ushort f2bf(float f) {
    unsigned u = __float_as_uint(f);
    return (ushort)((u + 0x7FFF + ((u >> 16) & 1)) >> 16);  // RNE
}

// binning: bin = node >> 9, 196 bins of 512 nodes, fixed capacity per bin
#define NBINS 196
#define CAP 7680                 // max used ~6420 + pads ~800 + 16 tail < 7680
#define EPB 2560
#define NBLK 469                 // ceil(1200000/2560)

// ---------------- workspace layout (bytes), flat, no overlays (~45 MB of 268 MB)
#define OFF_CNT    0             // int[100000]
#define OFF_ENDP   400128        // int[100000]
#define OFF_DINV   800256        // float[100000]
#define OFF_CUR    1200384       // int[392] global bin cursors
#define OFF_PKW    1202048       // ushort[2*1024*8] = 32 KB packed B-fragments
#define OFF_SRCS   1234816       // int[196*7680]    = 6.02 MB (final, dst-binned)
#define OFF_NRMS   7255936       // ushort[196*7680] = 3.01 MB
#define OFF_SBIN   10266496      // ushort[196*7680] = 3.01 MB staging
#define OFF_DBIN   13277056      // int[196*7680]    = 6.02 MB staging
#define OFF_EMBBF  19298176      // ushort[6.4M] = 12.8 MB
#define OFF_HBF    32098176      // ushort[6.4M] = 12.8 MB -> ends 44,898,176

// blocks 0-7: pack W into B-fragment order; block 8: init cursors;
// blocks 9+: emb f32 -> bf16
__global__ __launch_bounds__(256) void prep(const float* __restrict__ W10,
                                            const float* __restrict__ W11,
                                            const float* __restrict__ W20,
                                            const float* __restrict__ W21,
                                            ushort* __restrict__ pk,
                                            int* __restrict__ cur,
                                            const float* __restrict__ emb,
                                            ushort* __restrict__ emb_bf) {
    int b = blockIdx.x;
    int t = threadIdx.x;
    if (b < 8) {
        int idx = b * 256 + t;   // [0, 2048)
        int layer = idx >> 10;
        int rest = idx & 1023;
        int f = rest >> 6, L = rest & 63;
        int n = (f & 3) * 16 + (L & 15);
        int kb = (f >> 2) * 32 + ((L >> 4) << 3);
#pragma unroll
        for (int j = 0; j < 8; ++j) {
            int k = kb + j;
            const float* W = layer ? ((k < 64) ? W20 : W21) : ((k < 64) ? W10 : W11);
            pk[idx * 8 + j] = f2bf(W[(k & 63) * 64 + n]);
        }
    } else if (b == 8) {
        for (int i = t; i < 2 * NBINS; i += 256)
            cur[i] = (i < NBINS ? i : i - NBINS) * CAP;
    } else {
        int i = ((b - 9) * 256 + t) * 8;
        float4 v0 = *(const float4*)(emb + i);
        float4 v1 = *(const float4*)(emb + i + 4);
        uint4 o;
        o.x = (uint)f2bf(v0.x) | ((uint)f2bf(v0.y) << 16);
        o.y = (uint)f2bf(v0.z) | ((uint)f2bf(v0.w) << 16);
        o.z = (uint)f2bf(v1.x) | ((uint)f2bf(v1.y) << 16);
        o.w = (uint)f2bf(v1.z) | ((uint)f2bf(v1.w) << 16);
        *(uint4*)(emb_bf + i) = o;
    }
}

// single-pass binned counting sort: LDS hist -> chunk reservation -> scatter.
__global__ __launch_bounds__(256) void binsort(const int* __restrict__ row,
                                               const int* __restrict__ col,
                                               int* __restrict__ cur,
                                               ushort* __restrict__ sbinned,
                                               int* __restrict__ dbinned) {
    __shared__ int2 ecache[EPB];               // 20 KB
    __shared__ int sh[NBINS], dh[NBINS];
    __shared__ int sbase[NBINS], dbase[NBINS];
    int t = threadIdx.x;
    if (t < NBINS) { sh[t] = 0; dh[t] = 0; }
    __syncthreads();
    int base = blockIdx.x * EPB;
    for (int k = 0; k < EPB / 256; ++k) {
        int e = base + k * 256 + t;
        int s = -1, d = -1;
        if (e < N_EDGES) { s = row[e]; d = col[e]; }
        ecache[k * 256 + t] = make_int2(s, d);
        if (s >= 0 && s != d) {
            atomicAdd(&sh[s >> 9], 1);
            atomicAdd(&dh[d >> 9], 1);
        }
    }
    __syncthreads();
    if (t < NBINS) {
        sbase[t] = atomicAdd(&cur[t], sh[t]);
        dbase[t] = atomicAdd(&cur[NBINS + t], dh[t]);
    }
    __syncthreads();
    for (int k = 0; k < EPB / 256; ++k) {
        int2 p = ecache[k * 256 + t];
        int s = p.x, d = p.y;
        if (s >= 0 && s != d) {
            int ss = atomicAdd(&sbase[s >> 9], 1);
            sbinned[ss] = (ushort)(s & 511);
            int ds = atomicAdd(&dbase[d >> 9], 1);
            dbinned[ds] = (s << 9) | (d & 511);
        }
    }
}

// per src-bin per-node histogram -> dinv (512 threads, 1 node/thread)
__global__ __launch_bounds__(512) void binD1(const ushort* __restrict__ sbinned,
                                             const int* __restrict__ cur,
                                             float* __restrict__ dinv) {
    __shared__ int hist[512];
    int t = threadIdx.x;
    hist[t] = 0;
    __syncthreads();
    int b = blockIdx.x;
    int start = b * CAP;
    int end = cur[b];
    for (int i = start + t; i < end; i += 512)
        atomicAdd(&hist[sbinned[i]], 1);
    __syncthreads();
    int n0 = (b << 9) + t;
    if (n0 < N_NODES) dinv[n0] = hist[t] ? rsqrtf((float)hist[t]) : 0.0f;
}

// per dst-bin: hist + scan of 4-aligned counts -> cnt/endp + srcs/nrms scatter
__global__ __launch_bounds__(512) void binD2(const int* __restrict__ dbinned,
                                             const int* __restrict__ cur,
                                             const float* __restrict__ dinv,
                                             int* __restrict__ cnt,
                                             int* __restrict__ endp,
                                             int* __restrict__ srcs,
                                             ushort* __restrict__ nrms) {
    __shared__ int hist[512];
    __shared__ int lcur[512];
    __shared__ int tot_s;
    int t = threadIdx.x;
    hist[t] = 0;
    __syncthreads();
    int b = blockIdx.x;
    int start = b * CAP;
    int end = cur[NBINS + b];
    for (int i = start + t; i < end; i += 512)
        atomicAdd(&hist[dbinned[i] & 511], 1);
    __syncthreads();
    int o0 = hist[t];
    int A0 = (o0 + 3) & ~3;
    __syncthreads();
    hist[t] = A0;
    __syncthreads();
    for (int off = 1; off < 512; off <<= 1) {
        int v = (t >= off) ? hist[t - off] : 0;
        __syncthreads();
        hist[t] += v;
        __syncthreads();
    }
    int e0 = hist[t] - A0;   // exclusive (aligned)
    if (t == 511) tot_s = hist[511];
    lcur[t] = start + e0;
    int n0 = (b << 9) + t;
    if (n0 < N_NODES) { cnt[n0] = o0; endp[n0] = start + e0 + o0; }
    __syncthreads();
    for (int i = start + t; i < end; i += 512) {
        int p = dbinned[i];
        int s = p >> 9, dl = p & 511;
        int slot = atomicAdd(&lcur[dl], 1);
        srcs[slot] = s;
        nrms[slot] = f2bf(-dinv[s] * dinv[(b << 9) + dl]);
    }
    __syncthreads();
    // zero-fill per-node alignment pads
    for (int k = o0; k < A0; ++k) { srcs[start + e0 + k] = 0; nrms[start + e0 + k] = 0; }
    // zero-fill 16-slot bin tail (layer's straight-line 2x8 chunks may overread)
    if (t < 16) { srcs[start + tot_s + t] = 0; nrms[start + tot_s + t] = 0; }
}

// Fused layer: 16 nodes/wave; 4 edges/gather-instr (quarter-wave per edge,
// 4 features/lane). PAIR-INTERLEAVED: two nodes' chunks issue back-to-back
// (24 vmem in flight) before either node's reduce chain.
#define NPW 16
#define WPB 2
#define NPB (NPW * WPB)                       // 32
#define LB2 ((N_NODES + NPB - 1) / NPB)       // 3125

__global__ __launch_bounds__(128, 8) void cheb_layer(const ushort* __restrict__ x,
                                                     const int* __restrict__ srcs,
                                                     const ushort* __restrict__ nrms,
                                                     const int* __restrict__ endp,
                                                     const int* __restrict__ cnt,
                                                     const ushort* __restrict__ pk,
                                                     const float* __restrict__ bias,
                                                     ushort* __restrict__ out_bf,
                                                     float* __restrict__ out_f32,
                                                     int last) {
    __shared__ ushort sA[WPB][16][136];   // 8.7 KB

    int t = threadIdx.x;
    int lane = t & 63, wid = t >> 6;
    int c = lane & 15, q = lane >> 4;
    int qd = q, fg = c;
    int nb = blockIdx.x * NPB + wid * NPW;

    int nend = 0, ncnt = 0;
    if (lane < NPW && nb + lane < N_NODES) {
        nend = endp[nb + lane];
        ncnt = cnt[nb + lane];
    }

    const uint2* xr = (const uint2*)x;   // row = 16 uint2 (64 bf16)

    auto chunk8 = [&](int eb, int eendL, float& a0, float& a1, float& a2, float& a3) {
        int4 sv = *(const int4*)(srcs + eb);       // edges eb..eb+3 (uniform)
        int4 sw = *(const int4*)(srcs + eb + 4);   // edges eb+4..eb+7
        uint2 nv = *(const uint2*)(nrms + eb);
        uint2 nw = *(const uint2*)(nrms + eb + 4);
        int sA01 = (qd & 1) ? sv.y : sv.x;
        int sA23 = (qd & 1) ? sv.w : sv.z;
        int srcA = (qd & 2) ? sA23 : sA01;
        int sB01 = (qd & 1) ? sw.y : sw.x;
        int sB23 = (qd & 1) ? sw.w : sw.z;
        int srcB = (qd & 2) ? sB23 : sB01;
        uint nAp = (qd & 2) ? nv.y : nv.x;
        uint nBp = (qd & 2) ? nw.y : nw.x;
        float nAf = __uint_as_float((qd & 1) ? (nAp & 0xffff0000u) : (nAp << 16));
        float nBf = __uint_as_float((qd & 1) ? (nBp & 0xffff0000u) : (nBp << 16));
        nAf = (eb + qd < eendL) ? nAf : 0.0f;
        nBf = (eb + 4 + qd < eendL) ? nBf : 0.0f;
        uint2 gA = xr[(size_t)srcA * 16 + fg];
        uint2 gB = xr[(size_t)srcB * 16 + fg];
        a0 = fmaf(nAf, __uint_as_float(gA.x << 16), a0);
        a1 = fmaf(nAf, __uint_as_float(gA.x & 0xffff0000u), a1);
        a2 = fmaf(nAf, __uint_as_float(gA.y << 16), a2);
        a3 = fmaf(nAf, __uint_as_float(gA.y & 0xffff0000u), a3);
        a0 = fmaf(nBf, __uint_as_float(gB.x << 16), a0);
        a1 = fmaf(nBf, __uint_as_float(gB.x & 0xffff0000u), a1);
        a2 = fmaf(nBf, __uint_as_float(gB.y << 16), a2);
        a3 = fmaf(nBf, __uint_as_float(gB.y & 0xffff0000u), a3);
    };

#pragma unroll
    for (int gp = 0; gp < NPW; gp += 2) {
        int cn0 = __builtin_amdgcn_readlane(ncnt, gp);
        int ee0 = __builtin_amdgcn_readlane(nend, gp);
        int cn1 = __builtin_amdgcn_readlane(ncnt, gp + 1);
        int ee1 = __builtin_amdgcn_readlane(nend, gp + 1);
        int s0 = ee0 - cn0, s1 = ee1 - cn1;   // 4-aligned starts
        float a0 = 0, a1 = 0, a2 = 0, a3 = 0;
        float b0 = 0, b1 = 0, b2 = 0, b3 = 0;

        // static 2x8-edge chunks per node, pair-interleaved (masked; safe via tail)
        chunk8(s0,     ee0, a0, a1, a2, a3);
        chunk8(s1,     ee1, b0, b1, b2, b3);
        chunk8(s0 + 8, ee0, a0, a1, a2, a3);
        chunk8(s1 + 8, ee1, b0, b1, b2, b3);
        // rare heavy nodes (cn > 16)
        for (int e = s0 + 16; e < ee0; e += 8) chunk8(e, ee0, a0, a1, a2, a3);
        for (int e = s1 + 16; e < ee1; e += 8) chunk8(e, ee1, b0, b1, b2, b3);

        // interleaved cross-quarter reductions for both nodes
        a0 += __shfl_xor(a0, 16, 64); b0 += __shfl_xor(b0, 16, 64);
        a1 += __shfl_xor(a1, 16, 64); b1 += __shfl_xor(b1, 16, 64);
        a2 += __shfl_xor(a2, 16, 64); b2 += __shfl_xor(b2, 16, 64);
        a3 += __shfl_xor(a3, 16, 64); b3 += __shfl_xor(b3, 16, 64);
        a0 += __shfl_xor(a0, 32, 64); b0 += __shfl_xor(b0, 32, 64);
        a1 += __shfl_xor(a1, 32, 64); b1 += __shfl_xor(b1, 32, 64);
        a2 += __shfl_xor(a2, 32, 64); b2 += __shfl_xor(b2, 32, 64);
        a3 += __shfl_xor(a3, 32, 64); b3 += __shfl_xor(b3, 32, 64);

        int node0 = nb + gp, node1 = nb + gp + 1;
        int ni0 = (node0 < N_NODES) ? node0 : 0;
        int ni1 = (node1 < N_NODES) ? node1 : 0;
        if (qd == 0) {
            uint2 xv0 = xr[(size_t)ni0 * 16 + fg];
            uint2 xv1 = xr[(size_t)ni1 * 16 + fg];
            *(uint2*)&sA[wid][gp][4 * fg] = xv0;
            *(uint2*)&sA[wid][gp + 1][4 * fg] = xv1;
        }
        if (qd == 1) {
            uint2 p0, p1;
            p0.x = (uint)f2bf(a0) | ((uint)f2bf(a1) << 16);
            p0.y = (uint)f2bf(a2) | ((uint)f2bf(a3) << 16);
            p1.x = (uint)f2bf(b0) | ((uint)f2bf(b1) << 16);
            p1.y = (uint)f2bf(b2) | ((uint)f2bf(b3) << 16);
            *(uint2*)&sA[wid][gp][64 + 4 * fg] = p0;
            *(uint2*)&sA[wid][gp + 1][64 + 4 * fg] = p1;
        }
    }
    __builtin_amdgcn_wave_barrier();

    const short8* pk8 = (const short8*)pk;
    float4v C[4];
#pragma unroll
    for (int nt = 0; nt < 4; ++nt) {
        float b = bias[nt * 16 + c];
        C[nt] = (float4v){b, b, b, b};
    }
#pragma unroll
    for (int kt = 0; kt < 4; ++kt) {
        short8 af = *(const short8*)&sA[wid][c][kt * 32 + q * 8];
#pragma unroll
        for (int nt = 0; nt < 4; ++nt) {
            short8 bfr = pk8[(kt * 4 + nt) * 64 + lane];
            C[nt] = __builtin_amdgcn_mfma_f32_16x16x32_bf16(af, bfr, C[nt], 0, 0, 0);
        }
    }

#pragma unroll
    for (int nt = 0; nt < 4; ++nt) {
#pragma unroll
        for (int i = 0; i < 4; ++i) {
            int node = nb + q * 4 + i;
            if (node < N_NODES) {
                float v = C[nt][i];
                if (!last) {
                    v = fmaxf(v, 0.0f);
                    out_bf[(size_t)node * NF + nt * 16 + c] = f2bf(v);
                } else {
                    out_f32[(size_t)node * NF + nt * 16 + c] = v;
                }
            }
        }
    }
}

extern "C" void kernel_launch(void* const* d_in, const int* in_sizes, int n_in,
                              void* d_out, int out_size, void* d_ws, size_t ws_size,
                              hipStream_t stream) {
    const int* ei = (const int*)d_in[0];
    const int* row = ei;
    const int* col = ei + N_EDGES;
    const float* emb = (const float*)d_in[1];
    const float* W1_0 = (const float*)d_in[2];
    const float* W1_1 = (const float*)d_in[3];
    const float* b1 = (const float*)d_in[4];
    const float* W2_0 = (const float*)d_in[5];
    const float* W2_1 = (const float*)d_in[6];
    const float* b2 = (const float*)d_in[7];
    float* out = (float*)d_out;

    char* ws = (char*)d_ws;
    int* cnt = (int*)(ws + OFF_CNT);
    int* endp = (int*)(ws + OFF_ENDP);
    float* dinv = (float*)(ws + OFF_DINV);
    int* cur = (int*)(ws + OFF_CUR);
    ushort* pk = (ushort*)(ws + OFF_PKW);
    int* srcs = (int*)(ws + OFF_SRCS);
    ushort* nrms = (ushort*)(ws + OFF_NRMS);
    ushort* sbinned = (ushort*)(ws + OFF_SBIN);
    int* dbinned = (int*)(ws + OFF_DBIN);
    ushort* emb_bf = (ushort*)(ws + OFF_EMBBF);
    ushort* h_bf = (ushort*)(ws + OFF_HBF);

    prep<<<9 + 3125, 256, 0, stream>>>(W1_0, W1_1, W2_0, W2_1, pk, cur, emb, emb_bf);
    binsort<<<NBLK, 256, 0, stream>>>(row, col, cur, sbinned, dbinned);
    binD1<<<NBINS, 512, 0, stream>>>(sbinned, cur, dinv);
    binD2<<<NBINS, 512, 0, stream>>>(dbinned, cur, dinv, cnt, endp, srcs, nrms);

    cheb_layer<<<LB2, 128, 0, stream>>>(emb_bf, srcs, nrms, endp, cnt, pk, b1, h_bf, nullptr, 0);
    cheb_layer<<<LB2, 128, 0, stream>>>(h_bf, srcs, nrms, endp, cnt, pk + 8192, b2, nullptr, out, 1);
}